// Round 8
// baseline (5245.896 us; speedup 1.0000x reference)
//
#include <hip/hip_runtime.h>
#include <hip/hip_cooperative_groups.h>

namespace cg = cooperative_groups;

#define N_NODES 100000
#define E_EDGES 1600000
#define IN_CH   512
#define HID     256
#define OUT_CH  32
#define K_STEPS 10
#define EPAD    (E_EDGES + 8 * N_NODES)   // worst-case pad8 CSR length

typedef unsigned short u16;
typedef unsigned int   u32;

typedef __attribute__((ext_vector_type(8))) short bf16x8;
typedef __attribute__((ext_vector_type(4))) float f32x4;

__device__ __forceinline__ float b2f(u16 u) {
    union { u32 i; float f; } x; x.i = ((u32)u) << 16; return x.f;
}
__device__ __forceinline__ u16 f2b(float f) {
    union { float f; u32 u; } x; x.f = f;
    u32 r = x.u + 0x7fffu + ((x.u >> 16) & 1u);
    return (u16)(r >> 16);
}

// async global->LDS, 16B per lane. LDS dest is wave-uniform base + lane*16.
__device__ __forceinline__ void load_lds16(const void* g, void* l) {
    __builtin_amdgcn_global_load_lds(
        (const __attribute__((address_space(1))) unsigned int*)g,
        (__attribute__((address_space(3))) unsigned int*)l,
        16, 0, 0);
}

// ---------------- casts (weights only) ----------------

__global__ __launch_bounds__(256) void k_cast(const float* __restrict__ in, u16* __restrict__ out, int n4) {
    int i = blockIdx.x * 256 + threadIdx.x;
    if (i < n4) {
        float4 f = ((const float4*)in)[i];
        ushort4 u;
        u.x = f2b(f.x); u.y = f2b(f.y); u.z = f2b(f.z); u.w = f2b(f.w);
        ((ushort4*)out)[i] = u;
    }
}

// ---------------- preprocessing: degree, dinv, padded scan, CSR fill ----------------

__global__ __launch_bounds__(256) void k_count(const int* __restrict__ col, int* __restrict__ cnt) {
    int i = blockIdx.x * 256 + threadIdx.x;
    if (i < E_EDGES) atomicAdd(&cnt[col[i]], 1);
}

__global__ __launch_bounds__(256) void k_dinv(const int* __restrict__ cnt, float* __restrict__ dinv) {
    int i = blockIdx.x * 256 + threadIdx.x;
    if (i < N_NODES) dinv[i] = rsqrtf((float)(cnt[i] + 1));  // +1 self-loop
}

__device__ __forceinline__ int pad8(int v) { return (v + 7) & ~7; }

__global__ __launch_bounds__(256) void k_blocksum(const int* __restrict__ cnt, int* __restrict__ bs) {
    int b = blockIdx.x, t = threadIdx.x;
    int idx = b * 1024 + t * 4;
    int s = 0;
    #pragma unroll
    for (int j = 0; j < 4; ++j) if (idx + j < N_NODES) s += pad8(cnt[idx + j]);
    #pragma unroll
    for (int d = 32; d > 0; d >>= 1) s += __shfl_down(s, d, 64);
    __shared__ int smem[4];
    int lane = t & 63, w = t >> 6;
    if (lane == 0) smem[w] = s;
    __syncthreads();
    if (t == 0) bs[b] = smem[0] + smem[1] + smem[2] + smem[3];
}

__global__ void k_scanblocks(const int* __restrict__ bs, int* __restrict__ bo, int nb) {
    int t = threadIdx.x;  // 128 threads, nb <= 128
    int v = (t < nb) ? bs[t] : 0;
    int incl = v;
    int lane = t & 63, w = t >> 6;
    #pragma unroll
    for (int d = 1; d < 64; d <<= 1) { int tt = __shfl_up(incl, d, 64); if (lane >= d) incl += tt; }
    __shared__ int wsum[2];
    if (lane == 63) wsum[w] = incl;
    __syncthreads();
    int add = (w == 1) ? wsum[0] : 0;
    if (t < nb) bo[t] = add + incl - v;  // exclusive
}

__global__ __launch_bounds__(256) void k_scanwithin(const int* __restrict__ cnt, const int* __restrict__ bo,
                                                    int* __restrict__ off) {
    int b = blockIdx.x, t = threadIdx.x;
    int idx = b * 1024 + t * 4;
    int v[4]; int s = 0;
    #pragma unroll
    for (int j = 0; j < 4; ++j) { v[j] = (idx + j < N_NODES) ? pad8(cnt[idx + j]) : 0; s += v[j]; }
    int incl = s;
    int lane = t & 63, w = t >> 6;
    #pragma unroll
    for (int d = 1; d < 64; d <<= 1) { int tt = __shfl_up(incl, d, 64); if (lane >= d) incl += tt; }
    __shared__ int wsum[4];
    if (lane == 63) wsum[w] = incl;
    __syncthreads();
    int woff = 0;
    #pragma unroll
    for (int k = 0; k < 4; ++k) if (k < w) woff += wsum[k];
    int run = bo[b] + woff + incl - s;
    #pragma unroll
    for (int j = 0; j < 4; ++j) { if (idx + j < N_NODES) off[idx + j] = run; run += v[j]; }
}

__global__ __launch_bounds__(256) void k_total(const int* __restrict__ bo, const int* __restrict__ bs,
                                               int* __restrict__ off, int nb) {
    off[N_NODES] = bo[nb - 1] + bs[nb - 1];
}

// prefill padded CSR with the dummy node index (p[N] == 0 always)
__global__ __launch_bounds__(256) void k_filldummy(int* __restrict__ csr_row) {
    int i = blockIdx.x * 256 + threadIdx.x;
    if (i < EPAD) csr_row[i] = N_NODES;
}

__global__ __launch_bounds__(256) void k_fill(const int* __restrict__ row, const int* __restrict__ col,
                                              const int* __restrict__ off, int* __restrict__ cursor,
                                              int* __restrict__ csr_row) {
    int i = blockIdx.x * 256 + threadIdx.x;
    if (i < E_EDGES) {
        int c = col[i];
        int pos = off[c] + atomicAdd(&cursor[c], 1);
        csr_row[pos] = row[i];
    }
}

// ---------------- fused MLP: h1 = relu(xW1^T+b1); xres = h1 + relu(h1 Wr^T+br);
// ----------------            h0 = xres W2^T + b2; p0 = bf16(dinv .* h0)
// One block = 64 rows x full 256 hidden channels. 512 threads (8 waves, 2x4, 32x64/wave).
// LDS = 72KB -> 2 blocks/CU. launch_bounds (512,2): R2's (512,4) forced VGPR=64 ->
// ~43MB spill writes (WRITE_SIZE 18.8->62.5MB); LDS caps residency at 2 anyway.

// u16-element index into a [rows][256] bf16 LDS tile with 16B-chunk XOR swizzle
__device__ __forceinline__ int swz_idx(int row, int col) {
    return row * 256 + (((col >> 3) ^ (row & 7)) << 3) + (col & 7);
}

__global__ __launch_bounds__(512, 2) void fused_mlp(const float* __restrict__ A,      // x [M][512] fp32
                                                    const u16* __restrict__ W1b,      // [256][512] bf16
                                                    const float* __restrict__ b1,
                                                    const u16* __restrict__ Wrb,      // [256][256] bf16
                                                    const float* __restrict__ br,
                                                    const float* __restrict__ W2,     // [32][256] fp32
                                                    const float* __restrict__ b2,
                                                    const float* __restrict__ dinv,
                                                    float* __restrict__ h0,           // [M][32] fp32
                                                    u16* __restrict__ p0,             // [M][32] bf16
                                                    int M) {
    __shared__ __align__(16) u16 h1s[64 * 256];       // 32KB: h1, then xres (in place)
    __shared__ __align__(16) u16 Bs2[2][256 * 32];    // 32KB: W1b/Wrb K-tiles
    __shared__ __align__(16) u16 As2[2][64 * 32];     // 8KB:  x K-tiles
    u16* W2s = &Bs2[0][0];                            // [32][256] bf16 swizzled; Bs2[0] dead in phase C

    const int t = threadIdx.x;
    const int lane = t & 63, w = t >> 6;              // 8 waves
    const int wr = (w >> 2) * 32;                     // 0 / 32
    const int wc = (w & 3) * 64;                      // 0 / 64 / 128 / 192
    const int rr = lane >> 2, cc = lane & 3;
    const int fr = lane & 15, quad = lane >> 4;
    const int row0 = blockIdx.x * 64;

    f32x4 acc[2][4] = {};
    float4 fp;
    const int arow = t >> 3, aseg = t & 7;            // 64 rows x 8 float4 segs

    auto prefA = [&](int k0) {
        int gr = row0 + arow; if (gr > M - 1) gr = M - 1;
        fp = *(const float4*)&A[(size_t)gr * IN_CH + k0 + aseg * 4];
    };
    auto writeA = [&](int b) {
        u32 lo = (u32)f2b(fp.x) | ((u32)f2b(fp.y) << 16);
        u32 hi = (u32)f2b(fp.z) | ((u32)f2b(fp.w) << 16);
        *(uint2*)&As2[b][arow * 32 + aseg * 4] = make_uint2(lo, hi);
    };
    auto loadB1 = [&](int k0, int b) {   // W1b tile [256][32]
        #pragma unroll
        for (int rep = 0; rep < 2; ++rep) {
            int ii = w * 2 + rep;                       // 0..15
            int gc = ii * 16 + rr;                      // 0..255
            load_lds16(W1b + (size_t)gc * IN_CH + k0 + cc * 8, &Bs2[b][ii * 512]);
        }
    };
    auto loadB2 = [&](int k0, int b) {   // Wrb tile [256][32]
        #pragma unroll
        for (int rep = 0; rep < 2; ++rep) {
            int ii = w * 2 + rep;
            int gc = ii * 16 + rr;
            load_lds16(Wrb + (size_t)gc * HID + k0 + cc * 8, &Bs2[b][ii * 512]);
        }
    };

    // ---------- Phase A: h1 = relu(x @ W1^T + b1), K = 512 ----------
    prefA(0);
    loadB1(0, 0);
    writeA(0);
    __syncthreads();

    for (int it = 0; it < IN_CH / 32; ++it) {
        const int cur = it & 1;
        const bool more = (it < IN_CH / 32 - 1);
        if (more) prefA((it + 1) * 32);
        bf16x8 af[2], bfr[4];
        #pragma unroll
        for (int ti = 0; ti < 2; ++ti)
            af[ti] = *(const bf16x8*)&As2[cur][(wr + ti * 16 + fr) * 32 + quad * 8];
        #pragma unroll
        for (int tj = 0; tj < 4; ++tj)
            bfr[tj] = *(const bf16x8*)&Bs2[cur][(wc + tj * 16 + fr) * 32 + quad * 8];
        #pragma unroll
        for (int ti = 0; ti < 2; ++ti)
            #pragma unroll
            for (int tj = 0; tj < 4; ++tj)
                acc[ti][tj] = __builtin_amdgcn_mfma_f32_16x16x32_bf16(af[ti], bfr[tj], acc[ti][tj], 0, 0, 0);
        if (more) {
            loadB1((it + 1) * 32, cur ^ 1);
            writeA(cur ^ 1);
            __syncthreads();
        }
    }

    // epilogue A: relu+bias -> h1s (swizzled). Prefetch Wrb k0=0 concurrently.
    loadB2(0, 0);
    #pragma unroll
    for (int tj = 0; tj < 4; ++tj) {
        int col = wc + tj * 16 + fr;
        float bv = b1[col];
        #pragma unroll
        for (int ti = 0; ti < 2; ++ti)
            #pragma unroll
            for (int r = 0; r < 4; ++r) {
                int row = wr + ti * 16 + quad * 4 + r;
                h1s[swz_idx(row, col)] = f2b(fmaxf(acc[ti][tj][r] + bv, 0.f));
            }
    }
    __syncthreads();   // drains Wrb async load + h1 ds_writes

    // ---------- Phase B: h2 = relu(h1 @ Wr^T + br), K = 256; A-frags from h1s ----------
    #pragma unroll
    for (int ti = 0; ti < 2; ++ti)
        #pragma unroll
        for (int tj = 0; tj < 4; ++tj)
            #pragma unroll
            for (int r = 0; r < 4; ++r) acc[ti][tj][r] = 0.f;

    for (int it = 0; it < HID / 32; ++it) {
        const int cur = it & 1;
        const bool more = (it < HID / 32 - 1);
        if (more) loadB2((it + 1) * 32, cur ^ 1);
        bf16x8 af[2], bfr[4];
        #pragma unroll
        for (int ti = 0; ti < 2; ++ti) {
            int row = wr + ti * 16 + fr;
            af[ti] = *(const bf16x8*)&h1s[row * 256 + (((it * 4 + quad) ^ (row & 7)) << 3)];
        }
        #pragma unroll
        for (int tj = 0; tj < 4; ++tj)
            bfr[tj] = *(const bf16x8*)&Bs2[cur][(wc + tj * 16 + fr) * 32 + quad * 8];
        #pragma unroll
        for (int ti = 0; ti < 2; ++ti)
            #pragma unroll
            for (int tj = 0; tj < 4; ++tj)
                acc[ti][tj] = __builtin_amdgcn_mfma_f32_16x16x32_bf16(af[ti], bfr[tj], acc[ti][tj], 0, 0, 0);
        if (more) __syncthreads();
    }
    __syncthreads();   // all h1s frag reads + Bs2[0] reads complete

    // epilogue B: xres = h1 + relu(h2) (in place); stage W2 -> W2s (aliases dead Bs2[0])
    float4 wf[4];
    const int wrow = t >> 4, wseg = t & 15;           // 32 x 16 = 512 threads
    {
        const float* src = W2 + (size_t)wrow * HID + wseg * 16;
        wf[0] = *(const float4*)(src + 0);
        wf[1] = *(const float4*)(src + 4);
        wf[2] = *(const float4*)(src + 8);
        wf[3] = *(const float4*)(src + 12);
    }
    #pragma unroll
    for (int tj = 0; tj < 4; ++tj) {
        int col = wc + tj * 16 + fr;
        float bv = br[col];
        #pragma unroll
        for (int ti = 0; ti < 2; ++ti)
            #pragma unroll
            for (int r = 0; r < 4; ++r) {
                int row = wr + ti * 16 + quad * 4 + r;
                int idx = swz_idx(row, col);
                float h1v = b2f(h1s[idx]);
                h1s[idx] = f2b(h1v + fmaxf(acc[ti][tj][r] + bv, 0.f));
            }
    }
    {
        union { u16 s[8]; uint4 q; } pk;
        #pragma unroll
        for (int half = 0; half < 2; ++half) {
            float4 a = wf[half * 2], b = wf[half * 2 + 1];
            pk.s[0] = f2b(a.x); pk.s[1] = f2b(a.y); pk.s[2] = f2b(a.z); pk.s[3] = f2b(a.w);
            pk.s[4] = f2b(b.x); pk.s[5] = f2b(b.y); pk.s[6] = f2b(b.z); pk.s[7] = f2b(b.w);
            int chunk = wseg * 2 + half;
            *(uint4*)&W2s[wrow * 256 + ((chunk ^ (wrow & 7)) << 3)] = pk.q;
        }
    }
    __syncthreads();   // xres + W2s visible

    // ---------- Phase C: h0 = xres @ W2^T + b2 (K=256, N=32) ----------
    // wave w -> rows (w>>1)*16..+15, cols (w&1)*16..+15
    f32x4 acc3;
    #pragma unroll
    for (int r = 0; r < 4; ++r) acc3[r] = 0.f;

    const int crow = (w >> 1) * 16, ccol = (w & 1) * 16;
    for (int it = 0; it < HID / 32; ++it) {
        int ar = crow + fr;
        bf16x8 af = *(const bf16x8*)&h1s[ar * 256 + (((it * 4 + quad) ^ (ar & 7)) << 3)];
        int bc = ccol + fr;
        bf16x8 bfr = *(const bf16x8*)&W2s[bc * 256 + (((it * 4 + quad) ^ (bc & 7)) << 3)];
        acc3 = __builtin_amdgcn_mfma_f32_16x16x32_bf16(af, bfr, acc3, 0, 0, 0);
    }

    {
        int col = ccol + fr;
        float bv = b2[col];
        #pragma unroll
        for (int r = 0; r < 4; ++r) {
            int grow = row0 + crow + quad * 4 + r;
            if (grow < M) {
                float v = acc3[r] + bv;
                h0[(size_t)grow * OUT_CH + col] = v;
                p0[(size_t)grow * OUT_CH + col] = f2b(dinv[grow] * v);
            }
        }
    }
}

// ---------------- propagation ----------------
// p layout: u32[node][16], element l = channels (2l | 2l+1<<16); row N_NODES is all-zero.
// Cooperative version: all K steps in one kernel, grid.sync() between steps.
// csr/p stay L2-hot; csr-index prefetch pipeline overlaps the two serial latencies.

__global__ __launch_bounds__(256, 8) void k_prop_coop(const u32* __restrict__ p0buf, u32* __restrict__ p1buf,
                                                      float* __restrict__ hout, const float* __restrict__ h0,
                                                      const int* __restrict__ off, const int* __restrict__ csr_row,
                                                      const float* __restrict__ dinv) {
    cg::grid_group grid = cg::this_grid();
    const int t = threadIdx.x;
    const int l = t & 15;
    const int lbase = t & 48;
    const int grp0 = (int)(blockIdx.x * 16 + (t >> 4));
    const int ngrp = (int)gridDim.x * 16;

    const u32* pin = p0buf;
    u32* pout = p1buf;

    for (int s = 0; s < K_STEPS; ++s) {
        const bool last = (s == K_STEPS - 1);
        for (int gw = grp0; gw < N_NODES; gw += ngrp) {
            int sO = off[gw], e = off[gw + 1];        // multiple of 8
            float dv = dinv[gw];
            u32 selfp = pin[(size_t)gw * 16 + l];
            float2 h0v = ((const float2*)h0)[(size_t)gw * 16 + l];

            float acc0 = 0.f, acc1 = 0.f;
            int base = sO;
            int idx = (base < e) ? csr_row[base + (l & 7)] : 0;
            for (; base < e; base += 8) {
                int nb = base + 8;
                int idx_n = (nb < e) ? csr_row[nb + (l & 7)] : 0;  // next iter's indices in flight
                u32 v[8];
                #pragma unroll
                for (int i = 0; i < 8; ++i) {
                    int r = __shfl(idx, lbase + i, 64);
                    v[i] = pin[(size_t)r * 16 + l];   // 8 independent gathers in flight
                }
                #pragma unroll
                for (int i = 0; i < 8; ++i) {
                    union { u32 u; float f; } a, b;
                    a.u = v[i] << 16; b.u = v[i] & 0xffff0000u;
                    acc0 += a.f; acc1 += b.f;
                }
                idx = idx_n;
            }
            acc0 += b2f((u16)selfp);
            acc1 += b2f((u16)(selfp >> 16));
            float hc0 = 0.9f * dv * acc0 + 0.1f * h0v.x;
            float hc1 = 0.9f * dv * acc1 + 0.1f * h0v.y;
            if (last) {
                ((float2*)hout)[(size_t)gw * 16 + l] = make_float2(hc0, hc1);
            } else {
                pout[(size_t)gw * 16 + l] = (u32)f2b(dv * hc0) | ((u32)f2b(dv * hc1) << 16);
            }
        }
        __threadfence();
        grid.sync();
        const u32* np = pout;
        pout = (u32*)pin;
        pin = np;
    }
}

// classic single-step version (fallback if cooperative launch is unavailable)
__global__ __launch_bounds__(256) void k_prop(const u32* __restrict__ pin, u32* __restrict__ pout,
                                              float* __restrict__ hout, const float* __restrict__ h0,
                                              const int* __restrict__ off, const int* __restrict__ csr_row,
                                              const float* __restrict__ dinv, int last) {
    int t = threadIdx.x;
    int gw = blockIdx.x * 16 + (t >> 4);
    int l = t & 15;
    int lbase = t & 48;
    int s = off[gw], e = off[gw + 1];
    float dv = dinv[gw];
    u32 selfp = pin[(size_t)gw * 16 + l];
    float2 h0v = ((const float2*)h0)[(size_t)gw * 16 + l];

    float acc0 = 0.f, acc1 = 0.f;
    for (int base = s; base < e; base += 8) {
        int idx = csr_row[base + (l & 7)];
        u32 v[8];
        #pragma unroll
        for (int i = 0; i < 8; ++i) {
            int r = __shfl(idx, lbase + i, 64);
            v[i] = pin[(size_t)r * 16 + l];
        }
        #pragma unroll
        for (int i = 0; i < 8; ++i) {
            union { u32 u; float f; } a, b;
            a.u = v[i] << 16; b.u = v[i] & 0xffff0000u;
            acc0 += a.f; acc1 += b.f;
        }
    }
    acc0 += b2f((u16)selfp);
    acc1 += b2f((u16)(selfp >> 16));
    float hc0 = 0.9f * dv * acc0 + 0.1f * h0v.x;
    float hc1 = 0.9f * dv * acc1 + 0.1f * h0v.y;
    if (last) {
        ((float2*)hout)[(size_t)gw * 16 + l] = make_float2(hc0, hc1);
    } else {
        pout[(size_t)gw * 16 + l] = (u32)f2b(dv * hc0) | ((u32)f2b(dv * hc1) << 16);
    }
}

// ---------------- launch ----------------

extern "C" void kernel_launch(void* const* d_in, const int* in_sizes, int n_in,
                              void* d_out, int out_size, void* d_ws, size_t ws_size,
                              hipStream_t stream) {
    const float* x  = (const float*)d_in[0];
    const int*   ei = (const int*)d_in[1];      // [2][E]
    const float* W1 = (const float*)d_in[2];
    const float* b1 = (const float*)d_in[3];
    const float* Wr = (const float*)d_in[4];
    const float* br = (const float*)d_in[5];
    const float* W2 = (const float*)d_in[6];
    const float* b2 = (const float*)d_in[7];
    float* out = (float*)d_out;

    char* ws = (char*)d_ws;
    size_t off_b = 0;
    auto take = [&](size_t bytes) {
        void* p = ws + off_b;
        off_b += (bytes + 255) & ~(size_t)255;
        return p;
    };

    float* h0      = (float*)take((size_t)N_NODES * OUT_CH * 4);
    u16*   pA      = (u16*)  take((size_t)(N_NODES + 1) * OUT_CH * 2);
    u16*   pB      = (u16*)  take((size_t)(N_NODES + 1) * OUT_CH * 2);
    int*   csr_row = (int*)  take((size_t)EPAD * 4);
    float* dinv    = (float*)take((size_t)N_NODES * 4);
    int*   cnt     = (int*)  take((size_t)N_NODES * 4);
    int*   offs    = (int*)  take((size_t)(N_NODES + 1) * 4);
    int*   cursor  = (int*)  take((size_t)N_NODES * 4);
    int*   bs      = (int*)  take(1024);
    int*   bo      = (int*)  take(1024);
    u16*   W1b     = (u16*)  take((size_t)HID * IN_CH * 2);
    u16*   Wrb     = (u16*)  take((size_t)HID * HID * 2);

    const int* e_row = ei;
    const int* e_col = ei + E_EDGES;

    // 1) weight casts
    k_cast<<<(HID * IN_CH / 4 + 255) / 256, 256, 0, stream>>>(W1, W1b, HID * IN_CH / 4);
    k_cast<<<(HID * HID / 4 + 255) / 256, 256, 0, stream>>>(Wr, Wrb, HID * HID / 4);

    // 2) preprocessing (degree -> dinv must precede fused MLP; pad8 CSR for prop)
    hipMemsetAsync(cnt, 0, (size_t)N_NODES * 4, stream);
    hipMemsetAsync(cursor, 0, (size_t)N_NODES * 4, stream);
    hipMemsetAsync(pA + (size_t)N_NODES * OUT_CH, 0, OUT_CH * 2, stream);  // zero dummy row
    hipMemsetAsync(pB + (size_t)N_NODES * OUT_CH, 0, OUT_CH * 2, stream);
    const int NB = (N_NODES + 1023) / 1024;  // 98
    k_count<<<(E_EDGES + 255) / 256, 256, 0, stream>>>(e_col, cnt);
    k_dinv<<<(N_NODES + 255) / 256, 256, 0, stream>>>(cnt, dinv);
    k_blocksum<<<NB, 256, 0, stream>>>(cnt, bs);
    k_scanblocks<<<1, 128, 0, stream>>>(bs, bo, NB);
    k_scanwithin<<<NB, 256, 0, stream>>>(cnt, bo, offs);
    k_total<<<1, 1, 0, stream>>>(bo, bs, offs, NB);
    k_filldummy<<<(EPAD + 255) / 256, 256, 0, stream>>>(csr_row);
    k_fill<<<(E_EDGES + 255) / 256, 256, 0, stream>>>(e_row, e_col, offs, cursor, csr_row);

    // 3) fused MLP: x -> h1 -> xres -> h0, p0 (one pass over x; intermediates in LDS)
    fused_mlp<<<(N_NODES + 63) / 64, 512, 0, stream>>>(x, W1b, b1, Wrb, br, W2, b2,
                                                       dinv, h0, pA, N_NODES);

    // 4) propagation: all K steps in one cooperative kernel (grid.sync between steps)
    {
        const u32* cpA  = (const u32*)pA;
        u32*       cpB  = (u32*)pB;
        float*     hout = out;
        const float* ch0 = h0;
        const int* coff = offs;
        const int* ccsr = csr_row;
        const float* cdv = dinv;
        void* kargs[] = { (void*)&cpA, (void*)&cpB, (void*)&hout, (void*)&ch0,
                          (void*)&coff, (void*)&ccsr, (void*)&cdv };
        hipError_t cerr = hipLaunchCooperativeKernel((const void*)k_prop_coop,
                                                     dim3(2048), dim3(256), kargs, 0, stream);
        if (cerr != hipSuccess) {
            // fallback: 10 separate dispatches
            const u32* pin = (const u32*)pA;
            for (int s = 0; s < K_STEPS; ++s) {
                int last = (s == K_STEPS - 1);
                u32* pout = (u32*)((s & 1) ? pA : pB);
                k_prop<<<N_NODES / 16, 256, 0, stream>>>(pin, pout, out, h0, offs, csr_row, dinv, last);
                pin = pout;
            }
        }
    }
}

// Round 13
// 776.413 us; speedup vs baseline: 6.7566x; 6.7566x over previous
//
#include <hip/hip_runtime.h>

#define N_NODES 100000
#define E_EDGES 1600000
#define IN_CH   512
#define HID     256
#define OUT_CH  32
#define K_STEPS 10
#define EPAD    (E_EDGES + 8 * N_NODES)   // worst-case pad8 CSR length

typedef unsigned short u16;
typedef unsigned int   u32;

typedef __attribute__((ext_vector_type(8))) short bf16x8;
typedef __attribute__((ext_vector_type(4))) float f32x4;

__device__ __forceinline__ float b2f(u16 u) {
    union { u32 i; float f; } x; x.i = ((u32)u) << 16; return x.f;
}
__device__ __forceinline__ u16 f2b(float f) {
    union { float f; u32 u; } x; x.f = f;
    u32 r = x.u + 0x7fffu + ((x.u >> 16) & 1u);
    return (u16)(r >> 16);
}

// async global->LDS, 16B per lane. LDS dest is wave-uniform base + lane*16.
__device__ __forceinline__ void load_lds16(const void* g, void* l) {
    __builtin_amdgcn_global_load_lds(
        (const __attribute__((address_space(1))) unsigned int*)g,
        (__attribute__((address_space(3))) unsigned int*)l,
        16, 0, 0);
}

// ---------------- casts (weights only) ----------------

__global__ __launch_bounds__(256) void k_cast(const float* __restrict__ in, u16* __restrict__ out, int n4) {
    int i = blockIdx.x * 256 + threadIdx.x;
    if (i < n4) {
        float4 f = ((const float4*)in)[i];
        ushort4 u;
        u.x = f2b(f.x); u.y = f2b(f.y); u.z = f2b(f.z); u.w = f2b(f.w);
        ((ushort4*)out)[i] = u;
    }
}

// ---------------- preprocessing: degree, dinv, padded scan, CSR fill ----------------

__global__ __launch_bounds__(256) void k_count(const int* __restrict__ col, int* __restrict__ cnt) {
    int i = blockIdx.x * 256 + threadIdx.x;
    if (i < E_EDGES) atomicAdd(&cnt[col[i]], 1);
}

__global__ __launch_bounds__(256) void k_dinv(const int* __restrict__ cnt, float* __restrict__ dinv) {
    int i = blockIdx.x * 256 + threadIdx.x;
    if (i < N_NODES) dinv[i] = rsqrtf((float)(cnt[i] + 1));  // +1 self-loop
}

__device__ __forceinline__ int pad8(int v) { return (v + 7) & ~7; }

__global__ __launch_bounds__(256) void k_blocksum(const int* __restrict__ cnt, int* __restrict__ bs) {
    int b = blockIdx.x, t = threadIdx.x;
    int idx = b * 1024 + t * 4;
    int s = 0;
    #pragma unroll
    for (int j = 0; j < 4; ++j) if (idx + j < N_NODES) s += pad8(cnt[idx + j]);
    #pragma unroll
    for (int d = 32; d > 0; d >>= 1) s += __shfl_down(s, d, 64);
    __shared__ int smem[4];
    int lane = t & 63, w = t >> 6;
    if (lane == 0) smem[w] = s;
    __syncthreads();
    if (t == 0) bs[b] = smem[0] + smem[1] + smem[2] + smem[3];
}

__global__ void k_scanblocks(const int* __restrict__ bs, int* __restrict__ bo, int nb) {
    int t = threadIdx.x;  // 128 threads, nb <= 128
    int v = (t < nb) ? bs[t] : 0;
    int incl = v;
    int lane = t & 63, w = t >> 6;
    #pragma unroll
    for (int d = 1; d < 64; d <<= 1) { int tt = __shfl_up(incl, d, 64); if (lane >= d) incl += tt; }
    __shared__ int wsum[2];
    if (lane == 63) wsum[w] = incl;
    __syncthreads();
    int add = (w == 1) ? wsum[0] : 0;
    if (t < nb) bo[t] = add + incl - v;  // exclusive
}

__global__ __launch_bounds__(256) void k_scanwithin(const int* __restrict__ cnt, const int* __restrict__ bo,
                                                    int* __restrict__ off) {
    int b = blockIdx.x, t = threadIdx.x;
    int idx = b * 1024 + t * 4;
    int v[4]; int s = 0;
    #pragma unroll
    for (int j = 0; j < 4; ++j) { v[j] = (idx + j < N_NODES) ? pad8(cnt[idx + j]) : 0; s += v[j]; }
    int incl = s;
    int lane = t & 63, w = t >> 6;
    #pragma unroll
    for (int d = 1; d < 64; d <<= 1) { int tt = __shfl_up(incl, d, 64); if (lane >= d) incl += tt; }
    __shared__ int wsum[4];
    if (lane == 63) wsum[w] = incl;
    __syncthreads();
    int woff = 0;
    #pragma unroll
    for (int k = 0; k < 4; ++k) if (k < w) woff += wsum[k];
    int run = bo[b] + woff + incl - s;
    #pragma unroll
    for (int j = 0; j < 4; ++j) { if (idx + j < N_NODES) off[idx + j] = run; run += v[j]; }
}

__global__ __launch_bounds__(256) void k_total(const int* __restrict__ bo, const int* __restrict__ bs,
                                               int* __restrict__ off, int nb) {
    off[N_NODES] = bo[nb - 1] + bs[nb - 1];
}

// prefill padded CSR with the dummy node index (p[N] == 0 always)
__global__ __launch_bounds__(256) void k_filldummy(int* __restrict__ csr_row) {
    int i = blockIdx.x * 256 + threadIdx.x;
    if (i < EPAD) csr_row[i] = N_NODES;
}

__global__ __launch_bounds__(256) void k_fill(const int* __restrict__ row, const int* __restrict__ col,
                                              const int* __restrict__ off, int* __restrict__ cursor,
                                              int* __restrict__ csr_row) {
    int i = blockIdx.x * 256 + threadIdx.x;
    if (i < E_EDGES) {
        int c = col[i];
        int pos = off[c] + atomicAdd(&cursor[c], 1);
        csr_row[pos] = row[i];
    }
}

// ---------------- fused MLP: h1 = relu(xW1^T+b1); xres = h1 + relu(h1 Wr^T+br);
// ----------------            h0 = xres W2^T + b2; p0 = bf16(dinv .* h0)
// One block = 64 rows x full 256 hidden channels. 512 threads (8 waves, 2x4, 32x64/wave).
// LDS = 72KB -> 2 blocks/CU. launch_bounds (512,2): R2's (512,4) forced VGPR=64 ->
// ~43MB spill writes (WRITE_SIZE 18.8->62.5MB); LDS caps residency at 2 anyway.

// u16-element index into a [rows][256] bf16 LDS tile with 16B-chunk XOR swizzle
__device__ __forceinline__ int swz_idx(int row, int col) {
    return row * 256 + (((col >> 3) ^ (row & 7)) << 3) + (col & 7);
}

__global__ __launch_bounds__(512, 2) void fused_mlp(const float* __restrict__ A,      // x [M][512] fp32
                                                    const u16* __restrict__ W1b,      // [256][512] bf16
                                                    const float* __restrict__ b1,
                                                    const u16* __restrict__ Wrb,      // [256][256] bf16
                                                    const float* __restrict__ br,
                                                    const float* __restrict__ W2,     // [32][256] fp32
                                                    const float* __restrict__ b2,
                                                    const float* __restrict__ dinv,
                                                    float* __restrict__ h0,           // [M][32] fp32
                                                    u16* __restrict__ p0,             // [M][32] bf16
                                                    int M) {
    __shared__ __align__(16) u16 h1s[64 * 256];       // 32KB: h1, then xres (in place)
    __shared__ __align__(16) u16 Bs2[2][256 * 32];    // 32KB: W1b/Wrb K-tiles
    __shared__ __align__(16) u16 As2[2][64 * 32];     // 8KB:  x K-tiles
    u16* W2s = &Bs2[0][0];                            // [32][256] bf16 swizzled; Bs2[0] dead in phase C

    const int t = threadIdx.x;
    const int lane = t & 63, w = t >> 6;              // 8 waves
    const int wr = (w >> 2) * 32;                     // 0 / 32
    const int wc = (w & 3) * 64;                      // 0 / 64 / 128 / 192
    const int rr = lane >> 2, cc = lane & 3;
    const int fr = lane & 15, quad = lane >> 4;
    const int row0 = blockIdx.x * 64;

    f32x4 acc[2][4] = {};
    float4 fp;
    const int arow = t >> 3, aseg = t & 7;            // 64 rows x 8 float4 segs

    auto prefA = [&](int k0) {
        int gr = row0 + arow; if (gr > M - 1) gr = M - 1;
        fp = *(const float4*)&A[(size_t)gr * IN_CH + k0 + aseg * 4];
    };
    auto writeA = [&](int b) {
        u32 lo = (u32)f2b(fp.x) | ((u32)f2b(fp.y) << 16);
        u32 hi = (u32)f2b(fp.z) | ((u32)f2b(fp.w) << 16);
        *(uint2*)&As2[b][arow * 32 + aseg * 4] = make_uint2(lo, hi);
    };
    auto loadB1 = [&](int k0, int b) {   // W1b tile [256][32]
        #pragma unroll
        for (int rep = 0; rep < 2; ++rep) {
            int ii = w * 2 + rep;                       // 0..15
            int gc = ii * 16 + rr;                      // 0..255
            load_lds16(W1b + (size_t)gc * IN_CH + k0 + cc * 8, &Bs2[b][ii * 512]);
        }
    };
    auto loadB2 = [&](int k0, int b) {   // Wrb tile [256][32]
        #pragma unroll
        for (int rep = 0; rep < 2; ++rep) {
            int ii = w * 2 + rep;
            int gc = ii * 16 + rr;
            load_lds16(Wrb + (size_t)gc * HID + k0 + cc * 8, &Bs2[b][ii * 512]);
        }
    };

    // ---------- Phase A: h1 = relu(x @ W1^T + b1), K = 512 ----------
    prefA(0);
    loadB1(0, 0);
    writeA(0);
    __syncthreads();

    for (int it = 0; it < IN_CH / 32; ++it) {
        const int cur = it & 1;
        const bool more = (it < IN_CH / 32 - 1);
        if (more) prefA((it + 1) * 32);
        bf16x8 af[2], bfr[4];
        #pragma unroll
        for (int ti = 0; ti < 2; ++ti)
            af[ti] = *(const bf16x8*)&As2[cur][(wr + ti * 16 + fr) * 32 + quad * 8];
        #pragma unroll
        for (int tj = 0; tj < 4; ++tj)
            bfr[tj] = *(const bf16x8*)&Bs2[cur][(wc + tj * 16 + fr) * 32 + quad * 8];
        #pragma unroll
        for (int ti = 0; ti < 2; ++ti)
            #pragma unroll
            for (int tj = 0; tj < 4; ++tj)
                acc[ti][tj] = __builtin_amdgcn_mfma_f32_16x16x32_bf16(af[ti], bfr[tj], acc[ti][tj], 0, 0, 0);
        if (more) {
            loadB1((it + 1) * 32, cur ^ 1);
            writeA(cur ^ 1);
            __syncthreads();
        }
    }

    // epilogue A: relu+bias -> h1s (swizzled). Prefetch Wrb k0=0 concurrently.
    loadB2(0, 0);
    #pragma unroll
    for (int tj = 0; tj < 4; ++tj) {
        int col = wc + tj * 16 + fr;
        float bv = b1[col];
        #pragma unroll
        for (int ti = 0; ti < 2; ++ti)
            #pragma unroll
            for (int r = 0; r < 4; ++r) {
                int row = wr + ti * 16 + quad * 4 + r;
                h1s[swz_idx(row, col)] = f2b(fmaxf(acc[ti][tj][r] + bv, 0.f));
            }
    }
    __syncthreads();   // drains Wrb async load + h1 ds_writes

    // ---------- Phase B: h2 = relu(h1 @ Wr^T + br), K = 256; A-frags from h1s ----------
    #pragma unroll
    for (int ti = 0; ti < 2; ++ti)
        #pragma unroll
        for (int tj = 0; tj < 4; ++tj)
            #pragma unroll
            for (int r = 0; r < 4; ++r) acc[ti][tj][r] = 0.f;

    for (int it = 0; it < HID / 32; ++it) {
        const int cur = it & 1;
        const bool more = (it < HID / 32 - 1);
        if (more) loadB2((it + 1) * 32, cur ^ 1);
        bf16x8 af[2], bfr[4];
        #pragma unroll
        for (int ti = 0; ti < 2; ++ti) {
            int row = wr + ti * 16 + fr;
            af[ti] = *(const bf16x8*)&h1s[row * 256 + (((it * 4 + quad) ^ (row & 7)) << 3)];
        }
        #pragma unroll
        for (int tj = 0; tj < 4; ++tj)
            bfr[tj] = *(const bf16x8*)&Bs2[cur][(wc + tj * 16 + fr) * 32 + quad * 8];
        #pragma unroll
        for (int ti = 0; ti < 2; ++ti)
            #pragma unroll
            for (int tj = 0; tj < 4; ++tj)
                acc[ti][tj] = __builtin_amdgcn_mfma_f32_16x16x32_bf16(af[ti], bfr[tj], acc[ti][tj], 0, 0, 0);
        if (more) __syncthreads();
    }
    __syncthreads();   // all h1s frag reads + Bs2[0] reads complete

    // epilogue B: xres = h1 + relu(h2) (in place); stage W2 -> W2s (aliases dead Bs2[0])
    float4 wf[4];
    const int wrow = t >> 4, wseg = t & 15;           // 32 x 16 = 512 threads
    {
        const float* src = W2 + (size_t)wrow * HID + wseg * 16;
        wf[0] = *(const float4*)(src + 0);
        wf[1] = *(const float4*)(src + 4);
        wf[2] = *(const float4*)(src + 8);
        wf[3] = *(const float4*)(src + 12);
    }
    #pragma unroll
    for (int tj = 0; tj < 4; ++tj) {
        int col = wc + tj * 16 + fr;
        float bv = br[col];
        #pragma unroll
        for (int ti = 0; ti < 2; ++ti)
            #pragma unroll
            for (int r = 0; r < 4; ++r) {
                int row = wr + ti * 16 + quad * 4 + r;
                int idx = swz_idx(row, col);
                float h1v = b2f(h1s[idx]);
                h1s[idx] = f2b(h1v + fmaxf(acc[ti][tj][r] + bv, 0.f));
            }
    }
    {
        union { u16 s[8]; uint4 q; } pk;
        #pragma unroll
        for (int half = 0; half < 2; ++half) {
            float4 a = wf[half * 2], b = wf[half * 2 + 1];
            pk.s[0] = f2b(a.x); pk.s[1] = f2b(a.y); pk.s[2] = f2b(a.z); pk.s[3] = f2b(a.w);
            pk.s[4] = f2b(b.x); pk.s[5] = f2b(b.y); pk.s[6] = f2b(b.z); pk.s[7] = f2b(b.w);
            int chunk = wseg * 2 + half;
            *(uint4*)&W2s[wrow * 256 + ((chunk ^ (wrow & 7)) << 3)] = pk.q;
        }
    }
    __syncthreads();   // xres + W2s visible

    // ---------- Phase C: h0 = xres @ W2^T + b2 (K=256, N=32) ----------
    // wave w -> rows (w>>1)*16..+15, cols (w&1)*16..+15
    f32x4 acc3;
    #pragma unroll
    for (int r = 0; r < 4; ++r) acc3[r] = 0.f;

    const int crow = (w >> 1) * 16, ccol = (w & 1) * 16;
    for (int it = 0; it < HID / 32; ++it) {
        int ar = crow + fr;
        bf16x8 af = *(const bf16x8*)&h1s[ar * 256 + (((it * 4 + quad) ^ (ar & 7)) << 3)];
        int bc = ccol + fr;
        bf16x8 bfr = *(const bf16x8*)&W2s[bc * 256 + (((it * 4 + quad) ^ (bc & 7)) << 3)];
        acc3 = __builtin_amdgcn_mfma_f32_16x16x32_bf16(af, bfr, acc3, 0, 0, 0);
    }

    {
        int col = ccol + fr;
        float bv = b2[col];
        #pragma unroll
        for (int r = 0; r < 4; ++r) {
            int grow = row0 + crow + quad * 4 + r;
            if (grow < M) {
                float v = acc3[r] + bv;
                h0[(size_t)grow * OUT_CH + col] = v;
                p0[(size_t)grow * OUT_CH + col] = f2b(dinv[grow] * v);
            }
        }
    }
}

// ---------------- propagation: 16 lanes/node, pad8 CSR ----------------
// p layout: u32[node][16], element l = channels (2l | 2l+1<<16); row N_NODES is all-zero.
// R8 lesson: coop + __launch_bounds__(256,8) -> VGPR=28 -> serialized gathers, 8.4x slower.
// 10-dispatch structure (measured 56us/step) + 16-gather main loop (R1 showed per-edge
// throughput scales with in-flight depth: 42 vs 35 M edges/s at 16 vs 8 in flight).
// NO min-waves launch bound: compiler must keep 16 dest regs + addresses live.

__global__ __launch_bounds__(256) void k_prop(const u32* __restrict__ pin, u32* __restrict__ pout,
                                              float* __restrict__ hout, const float* __restrict__ h0,
                                              const int* __restrict__ off, const int* __restrict__ csr_row,
                                              const float* __restrict__ dinv, int last) {
    int t = threadIdx.x;
    int gw = blockIdx.x * 16 + (t >> 4);     // node (grid = N/16 blocks, N%16==0)
    int l = t & 15;
    int lbase = t & 48;
    int s = off[gw], e = off[gw + 1];        // (e-s) % 8 == 0 by construction
    float dv = dinv[gw];
    u32 selfp = pin[(size_t)gw * 16 + l];
    float2 h0v = ((const float2*)h0)[(size_t)gw * 16 + l];

    float acc0 = 0.f, acc1 = 0.f;
    int base = s;
    // main loop: 16 edges per iter, 16 independent gathers in flight
    for (; base + 16 <= e; base += 16) {
        int idx = csr_row[base + l];          // 16 distinct indices, 64B coalesced per group
        u32 v[16];
        #pragma unroll
        for (int i = 0; i < 16; ++i) {
            int r = __shfl(idx, lbase + i, 64);
            v[i] = pin[(size_t)r * 16 + l];
        }
        #pragma unroll
        for (int i = 0; i < 16; ++i) {
            union { u32 u; float f; } a, b;
            a.u = v[i] << 16; b.u = v[i] & 0xffff0000u;
            acc0 += a.f; acc1 += b.f;
        }
    }
    if (base < e) {   // 8-edge tail (pad8 guarantees exactly one)
        int idx = csr_row[base + (l & 7)];    // lanes 8-15 duplicate 0-7 (broadcast-coalesced)
        u32 v[8];
        #pragma unroll
        for (int i = 0; i < 8; ++i) {
            int r = __shfl(idx, lbase + i, 64);
            v[i] = pin[(size_t)r * 16 + l];
        }
        #pragma unroll
        for (int i = 0; i < 8; ++i) {
            union { u32 u; float f; } a, b;
            a.u = v[i] << 16; b.u = v[i] & 0xffff0000u;
            acc0 += a.f; acc1 += b.f;
        }
    }
    acc0 += b2f((u16)selfp);
    acc1 += b2f((u16)(selfp >> 16));
    float hc0 = 0.9f * dv * acc0 + 0.1f * h0v.x;
    float hc1 = 0.9f * dv * acc1 + 0.1f * h0v.y;
    if (last) {
        ((float2*)hout)[(size_t)gw * 16 + l] = make_float2(hc0, hc1);
    } else {
        pout[(size_t)gw * 16 + l] = (u32)f2b(dv * hc0) | ((u32)f2b(dv * hc1) << 16);
    }
}

// ---------------- launch ----------------

extern "C" void kernel_launch(void* const* d_in, const int* in_sizes, int n_in,
                              void* d_out, int out_size, void* d_ws, size_t ws_size,
                              hipStream_t stream) {
    const float* x  = (const float*)d_in[0];
    const int*   ei = (const int*)d_in[1];      // [2][E]
    const float* W1 = (const float*)d_in[2];
    const float* b1 = (const float*)d_in[3];
    const float* Wr = (const float*)d_in[4];
    const float* br = (const float*)d_in[5];
    const float* W2 = (const float*)d_in[6];
    const float* b2 = (const float*)d_in[7];
    float* out = (float*)d_out;

    char* ws = (char*)d_ws;
    size_t off_b = 0;
    auto take = [&](size_t bytes) {
        void* p = ws + off_b;
        off_b += (bytes + 255) & ~(size_t)255;
        return p;
    };

    float* h0      = (float*)take((size_t)N_NODES * OUT_CH * 4);
    u16*   pA      = (u16*)  take((size_t)(N_NODES + 1) * OUT_CH * 2);
    u16*   pB      = (u16*)  take((size_t)(N_NODES + 1) * OUT_CH * 2);
    int*   csr_row = (int*)  take((size_t)EPAD * 4);
    float* dinv    = (float*)take((size_t)N_NODES * 4);
    int*   cnt     = (int*)  take((size_t)N_NODES * 4);
    int*   offs    = (int*)  take((size_t)(N_NODES + 1) * 4);
    int*   cursor  = (int*)  take((size_t)N_NODES * 4);
    int*   bs      = (int*)  take(1024);
    int*   bo      = (int*)  take(1024);
    u16*   W1b     = (u16*)  take((size_t)HID * IN_CH * 2);
    u16*   Wrb     = (u16*)  take((size_t)HID * HID * 2);

    const int* e_row = ei;
    const int* e_col = ei + E_EDGES;

    // 1) weight casts
    k_cast<<<(HID * IN_CH / 4 + 255) / 256, 256, 0, stream>>>(W1, W1b, HID * IN_CH / 4);
    k_cast<<<(HID * HID / 4 + 255) / 256, 256, 0, stream>>>(Wr, Wrb, HID * HID / 4);

    // 2) preprocessing (degree -> dinv must precede fused MLP; pad8 CSR for prop)
    hipMemsetAsync(cnt, 0, (size_t)N_NODES * 4, stream);
    hipMemsetAsync(cursor, 0, (size_t)N_NODES * 4, stream);
    hipMemsetAsync(pA + (size_t)N_NODES * OUT_CH, 0, OUT_CH * 2, stream);  // zero dummy row
    hipMemsetAsync(pB + (size_t)N_NODES * OUT_CH, 0, OUT_CH * 2, stream);
    const int NB = (N_NODES + 1023) / 1024;  // 98
    k_count<<<(E_EDGES + 255) / 256, 256, 0, stream>>>(e_col, cnt);
    k_dinv<<<(N_NODES + 255) / 256, 256, 0, stream>>>(cnt, dinv);
    k_blocksum<<<NB, 256, 0, stream>>>(cnt, bs);
    k_scanblocks<<<1, 128, 0, stream>>>(bs, bo, NB);
    k_scanwithin<<<NB, 256, 0, stream>>>(cnt, bo, offs);
    k_total<<<1, 1, 0, stream>>>(bo, bs, offs, NB);
    k_filldummy<<<(EPAD + 255) / 256, 256, 0, stream>>>(csr_row);
    k_fill<<<(E_EDGES + 255) / 256, 256, 0, stream>>>(e_row, e_col, offs, cursor, csr_row);

    // 3) fused MLP: x -> h1 -> xres -> h0, p0 (one pass over x; intermediates in LDS)
    fused_mlp<<<(N_NODES + 63) / 64, 512, 0, stream>>>(x, W1b, b1, Wrb, br, W2, b2,
                                                       dinv, h0, pA, N_NODES);

    // 4) propagation: K steps on packed bf16 p, final step writes fp32 h to out
    const u32* pin = (const u32*)pA;
    for (int s = 0; s < K_STEPS; ++s) {
        int last = (s == K_STEPS - 1);
        u32* pout = (u32*)((s & 1) ? pA : pB);
        k_prop<<<N_NODES / 16, 256, 0, stream>>>(pin, pout, out, h0, offs, csr_row, dinv, last);
        pin = pout;
    }
}

// Round 15
// 761.218 us; speedup vs baseline: 6.8914x; 1.0200x over previous
//
#include <hip/hip_runtime.h>

#define N_NODES 100000
#define E_EDGES 1600000
#define IN_CH   512
#define HID     256
#define OUT_CH  32
#define K_STEPS 10
#define EPAD    (E_EDGES + 8 * N_NODES)   // worst-case pad8 CSR length

typedef unsigned short u16;
typedef unsigned int   u32;

typedef __attribute__((ext_vector_type(8))) short bf16x8;
typedef __attribute__((ext_vector_type(4))) float f32x4;

__device__ __forceinline__ float b2f(u16 u) {
    union { u32 i; float f; } x; x.i = ((u32)u) << 16; return x.f;
}
__device__ __forceinline__ u16 f2b(float f) {
    union { float f; u32 u; } x; x.f = f;
    u32 r = x.u + 0x7fffu + ((x.u >> 16) & 1u);
    return (u16)(r >> 16);
}

// async global->LDS. LDS dest is wave-uniform base + lane*size; global src is per-lane.
__device__ __forceinline__ void load_lds16(const void* g, void* l) {
    __builtin_amdgcn_global_load_lds(
        (const __attribute__((address_space(1))) unsigned int*)g,
        (__attribute__((address_space(3))) unsigned int*)l,
        16, 0, 0);
}
__device__ __forceinline__ void load_lds4(const void* g, void* l) {
    __builtin_amdgcn_global_load_lds(
        (const __attribute__((address_space(1))) unsigned int*)g,
        (__attribute__((address_space(3))) unsigned int*)l,
        4, 0, 0);
}

// ---------------- casts (weights only) ----------------

__global__ __launch_bounds__(256) void k_cast(const float* __restrict__ in, u16* __restrict__ out, int n4) {
    int i = blockIdx.x * 256 + threadIdx.x;
    if (i < n4) {
        float4 f = ((const float4*)in)[i];
        ushort4 u;
        u.x = f2b(f.x); u.y = f2b(f.y); u.z = f2b(f.z); u.w = f2b(f.w);
        ((ushort4*)out)[i] = u;
    }
}

// ---------------- preprocessing: degree, dinv, padded scan, CSR fill ----------------

__global__ __launch_bounds__(256) void k_count(const int* __restrict__ col, int* __restrict__ cnt) {
    int i = blockIdx.x * 256 + threadIdx.x;
    if (i < E_EDGES) atomicAdd(&cnt[col[i]], 1);
}

__global__ __launch_bounds__(256) void k_dinv(const int* __restrict__ cnt, float* __restrict__ dinv) {
    int i = blockIdx.x * 256 + threadIdx.x;
    if (i < N_NODES) dinv[i] = rsqrtf((float)(cnt[i] + 1));  // +1 self-loop
}

__device__ __forceinline__ int pad8(int v) { return (v + 7) & ~7; }

__global__ __launch_bounds__(256) void k_blocksum(const int* __restrict__ cnt, int* __restrict__ bs) {
    int b = blockIdx.x, t = threadIdx.x;
    int idx = b * 1024 + t * 4;
    int s = 0;
    #pragma unroll
    for (int j = 0; j < 4; ++j) if (idx + j < N_NODES) s += pad8(cnt[idx + j]);
    #pragma unroll
    for (int d = 32; d > 0; d >>= 1) s += __shfl_down(s, d, 64);
    __shared__ int smem[4];
    int lane = t & 63, w = t >> 6;
    if (lane == 0) smem[w] = s;
    __syncthreads();
    if (t == 0) bs[b] = smem[0] + smem[1] + smem[2] + smem[3];
}

__global__ void k_scanblocks(const int* __restrict__ bs, int* __restrict__ bo, int nb) {
    int t = threadIdx.x;  // 128 threads, nb <= 128
    int v = (t < nb) ? bs[t] : 0;
    int incl = v;
    int lane = t & 63, w = t >> 6;
    #pragma unroll
    for (int d = 1; d < 64; d <<= 1) { int tt = __shfl_up(incl, d, 64); if (lane >= d) incl += tt; }
    __shared__ int wsum[2];
    if (lane == 63) wsum[w] = incl;
    __syncthreads();
    int add = (w == 1) ? wsum[0] : 0;
    if (t < nb) bo[t] = add + incl - v;  // exclusive
}

__global__ __launch_bounds__(256) void k_scanwithin(const int* __restrict__ cnt, const int* __restrict__ bo,
                                                    int* __restrict__ off) {
    int b = blockIdx.x, t = threadIdx.x;
    int idx = b * 1024 + t * 4;
    int v[4]; int s = 0;
    #pragma unroll
    for (int j = 0; j < 4; ++j) { v[j] = (idx + j < N_NODES) ? pad8(cnt[idx + j]) : 0; s += v[j]; }
    int incl = s;
    int lane = t & 63, w = t >> 6;
    #pragma unroll
    for (int d = 1; d < 64; d <<= 1) { int tt = __shfl_up(incl, d, 64); if (lane >= d) incl += tt; }
    __shared__ int wsum[4];
    if (lane == 63) wsum[w] = incl;
    __syncthreads();
    int woff = 0;
    #pragma unroll
    for (int k = 0; k < 4; ++k) if (k < w) woff += wsum[k];
    int run = bo[b] + woff + incl - s;
    #pragma unroll
    for (int j = 0; j < 4; ++j) { if (idx + j < N_NODES) off[idx + j] = run; run += v[j]; }
}

__global__ __launch_bounds__(256) void k_total(const int* __restrict__ bo, const int* __restrict__ bs,
                                               int* __restrict__ off, int nb) {
    off[N_NODES] = bo[nb - 1] + bs[nb - 1];
}

// prefill padded CSR with the dummy node index (p[N] == 0 always)
__global__ __launch_bounds__(256) void k_filldummy(int* __restrict__ csr_row) {
    int i = blockIdx.x * 256 + threadIdx.x;
    if (i < EPAD) csr_row[i] = N_NODES;
}

__global__ __launch_bounds__(256) void k_fill(const int* __restrict__ row, const int* __restrict__ col,
                                              const int* __restrict__ off, int* __restrict__ cursor,
                                              int* __restrict__ csr_row) {
    int i = blockIdx.x * 256 + threadIdx.x;
    if (i < E_EDGES) {
        int c = col[i];
        int pos = off[c] + atomicAdd(&cursor[c], 1);
        csr_row[pos] = row[i];
    }
}

// ---------------- fused MLP: h1 = relu(xW1^T+b1); xres = h1 + relu(h1 Wr^T+br);
// ----------------            h0 = xres W2^T + b2; p0 = bf16(dinv .* h0)
// One block = 64 rows x full 256 hidden channels. 512 threads (8 waves, 2x4, 32x64/wave).
// launch_bounds (512,4): MEASURED best (R2: 149us, VGPR=64, occ 38%, spills L2-absorbed).
// (512,2) measured WORSE (R13: 170us, VGPR=76, occ 20% -> residency loss beats spill gain).

// u16-element index into a [rows][256] bf16 LDS tile with 16B-chunk XOR swizzle
__device__ __forceinline__ int swz_idx(int row, int col) {
    return row * 256 + (((col >> 3) ^ (row & 7)) << 3) + (col & 7);
}

__global__ __launch_bounds__(512, 4) void fused_mlp(const float* __restrict__ A,      // x [M][512] fp32
                                                    const u16* __restrict__ W1b,      // [256][512] bf16
                                                    const float* __restrict__ b1,
                                                    const u16* __restrict__ Wrb,      // [256][256] bf16
                                                    const float* __restrict__ br,
                                                    const float* __restrict__ W2,     // [32][256] fp32
                                                    const float* __restrict__ b2,
                                                    const float* __restrict__ dinv,
                                                    float* __restrict__ h0,           // [M][32] fp32
                                                    u16* __restrict__ p0,             // [M][32] bf16
                                                    int M) {
    __shared__ __align__(16) u16 h1s[64 * 256];       // 32KB: h1, then xres (in place)
    __shared__ __align__(16) u16 Bs2[2][256 * 32];    // 32KB: W1b/Wrb K-tiles
    __shared__ __align__(16) u16 As2[2][64 * 32];     // 8KB:  x K-tiles
    u16* W2s = &Bs2[0][0];                            // [32][256] bf16 swizzled; Bs2[0] dead in phase C

    const int t = threadIdx.x;
    const int lane = t & 63, w = t >> 6;              // 8 waves
    const int wr = (w >> 2) * 32;                     // 0 / 32
    const int wc = (w & 3) * 64;                      // 0 / 64 / 128 / 192
    const int rr = lane >> 2, cc = lane & 3;
    const int fr = lane & 15, quad = lane >> 4;
    const int row0 = blockIdx.x * 64;

    f32x4 acc[2][4] = {};
    float4 fp;
    const int arow = t >> 3, aseg = t & 7;            // 64 rows x 8 float4 segs

    auto prefA = [&](int k0) {
        int gr = row0 + arow; if (gr > M - 1) gr = M - 1;
        fp = *(const float4*)&A[(size_t)gr * IN_CH + k0 + aseg * 4];
    };
    auto writeA = [&](int b) {
        u32 lo = (u32)f2b(fp.x) | ((u32)f2b(fp.y) << 16);
        u32 hi = (u32)f2b(fp.z) | ((u32)f2b(fp.w) << 16);
        *(uint2*)&As2[b][arow * 32 + aseg * 4] = make_uint2(lo, hi);
    };
    auto loadB1 = [&](int k0, int b) {   // W1b tile [256][32]
        #pragma unroll
        for (int rep = 0; rep < 2; ++rep) {
            int ii = w * 2 + rep;                       // 0..15
            int gc = ii * 16 + rr;                      // 0..255
            load_lds16(W1b + (size_t)gc * IN_CH + k0 + cc * 8, &Bs2[b][ii * 512]);
        }
    };
    auto loadB2 = [&](int k0, int b) {   // Wrb tile [256][32]
        #pragma unroll
        for (int rep = 0; rep < 2; ++rep) {
            int ii = w * 2 + rep;
            int gc = ii * 16 + rr;
            load_lds16(Wrb + (size_t)gc * HID + k0 + cc * 8, &Bs2[b][ii * 512]);
        }
    };

    // ---------- Phase A: h1 = relu(x @ W1^T + b1), K = 512 ----------
    prefA(0);
    loadB1(0, 0);
    writeA(0);
    __syncthreads();

    for (int it = 0; it < IN_CH / 32; ++it) {
        const int cur = it & 1;
        const bool more = (it < IN_CH / 32 - 1);
        if (more) prefA((it + 1) * 32);
        bf16x8 af[2], bfr[4];
        #pragma unroll
        for (int ti = 0; ti < 2; ++ti)
            af[ti] = *(const bf16x8*)&As2[cur][(wr + ti * 16 + fr) * 32 + quad * 8];
        #pragma unroll
        for (int tj = 0; tj < 4; ++tj)
            bfr[tj] = *(const bf16x8*)&Bs2[cur][(wc + tj * 16 + fr) * 32 + quad * 8];
        #pragma unroll
        for (int ti = 0; ti < 2; ++ti)
            #pragma unroll
            for (int tj = 0; tj < 4; ++tj)
                acc[ti][tj] = __builtin_amdgcn_mfma_f32_16x16x32_bf16(af[ti], bfr[tj], acc[ti][tj], 0, 0, 0);
        if (more) {
            loadB1((it + 1) * 32, cur ^ 1);
            writeA(cur ^ 1);
            __syncthreads();
        }
    }

    // epilogue A: relu+bias -> h1s (swizzled). Prefetch Wrb k0=0 concurrently.
    loadB2(0, 0);
    #pragma unroll
    for (int tj = 0; tj < 4; ++tj) {
        int col = wc + tj * 16 + fr;
        float bv = b1[col];
        #pragma unroll
        for (int ti = 0; ti < 2; ++ti)
            #pragma unroll
            for (int r = 0; r < 4; ++r) {
                int row = wr + ti * 16 + quad * 4 + r;
                h1s[swz_idx(row, col)] = f2b(fmaxf(acc[ti][tj][r] + bv, 0.f));
            }
    }
    __syncthreads();   // drains Wrb async load + h1 ds_writes

    // ---------- Phase B: h2 = relu(h1 @ Wr^T + br), K = 256; A-frags from h1s ----------
    #pragma unroll
    for (int ti = 0; ti < 2; ++ti)
        #pragma unroll
        for (int tj = 0; tj < 4; ++tj)
            #pragma unroll
            for (int r = 0; r < 4; ++r) acc[ti][tj][r] = 0.f;

    for (int it = 0; it < HID / 32; ++it) {
        const int cur = it & 1;
        const bool more = (it < HID / 32 - 1);
        if (more) loadB2((it + 1) * 32, cur ^ 1);
        bf16x8 af[2], bfr[4];
        #pragma unroll
        for (int ti = 0; ti < 2; ++ti) {
            int row = wr + ti * 16 + fr;
            af[ti] = *(const bf16x8*)&h1s[row * 256 + (((it * 4 + quad) ^ (row & 7)) << 3)];
        }
        #pragma unroll
        for (int tj = 0; tj < 4; ++tj)
            bfr[tj] = *(const bf16x8*)&Bs2[cur][(wc + tj * 16 + fr) * 32 + quad * 8];
        #pragma unroll
        for (int ti = 0; ti < 2; ++ti)
            #pragma unroll
            for (int tj = 0; tj < 4; ++tj)
                acc[ti][tj] = __builtin_amdgcn_mfma_f32_16x16x32_bf16(af[ti], bfr[tj], acc[ti][tj], 0, 0, 0);
        if (more) __syncthreads();
    }
    __syncthreads();   // all h1s frag reads + Bs2[0] reads complete

    // epilogue B: xres = h1 + relu(h2) (in place); stage W2 -> W2s (aliases dead Bs2[0])
    float4 wf[4];
    const int wrow = t >> 4, wseg = t & 15;           // 32 x 16 = 512 threads
    {
        const float* src = W2 + (size_t)wrow * HID + wseg * 16;
        wf[0] = *(const float4*)(src + 0);
        wf[1] = *(const float4*)(src + 4);
        wf[2] = *(const float4*)(src + 8);
        wf[3] = *(const float4*)(src + 12);
    }
    #pragma unroll
    for (int tj = 0; tj < 4; ++tj) {
        int col = wc + tj * 16 + fr;
        float bv = br[col];
        #pragma unroll
        for (int ti = 0; ti < 2; ++ti)
            #pragma unroll
            for (int r = 0; r < 4; ++r) {
                int row = wr + ti * 16 + quad * 4 + r;
                int idx = swz_idx(row, col);
                float h1v = b2f(h1s[idx]);
                h1s[idx] = f2b(h1v + fmaxf(acc[ti][tj][r] + bv, 0.f));
            }
    }
    {
        union { u16 s[8]; uint4 q; } pk;
        #pragma unroll
        for (int half = 0; half < 2; ++half) {
            float4 a = wf[half * 2], b = wf[half * 2 + 1];
            pk.s[0] = f2b(a.x); pk.s[1] = f2b(a.y); pk.s[2] = f2b(a.z); pk.s[3] = f2b(a.w);
            pk.s[4] = f2b(b.x); pk.s[5] = f2b(b.y); pk.s[6] = f2b(b.z); pk.s[7] = f2b(b.w);
            int chunk = wseg * 2 + half;
            *(uint4*)&W2s[wrow * 256 + ((chunk ^ (wrow & 7)) << 3)] = pk.q;
        }
    }
    __syncthreads();   // xres + W2s visible

    // ---------- Phase C: h0 = xres @ W2^T + b2 (K=256, N=32) ----------
    // wave w -> rows (w>>1)*16..+15, cols (w&1)*16..+15
    f32x4 acc3;
    #pragma unroll
    for (int r = 0; r < 4; ++r) acc3[r] = 0.f;

    const int crow = (w >> 1) * 16, ccol = (w & 1) * 16;
    for (int it = 0; it < HID / 32; ++it) {
        int ar = crow + fr;
        bf16x8 af = *(const bf16x8*)&h1s[ar * 256 + (((it * 4 + quad) ^ (ar & 7)) << 3)];
        int bc = ccol + fr;
        bf16x8 bfr = *(const bf16x8*)&W2s[bc * 256 + (((it * 4 + quad) ^ (bc & 7)) << 3)];
        acc3 = __builtin_amdgcn_mfma_f32_16x16x32_bf16(af, bfr, acc3, 0, 0, 0);
    }

    {
        int col = ccol + fr;
        float bv = b2[col];
        #pragma unroll
        for (int r = 0; r < 4; ++r) {
            int grow = row0 + crow + quad * 4 + r;
            if (grow < M) {
                float v = acc3[r] + bv;
                h0[(size_t)grow * OUT_CH + col] = v;
                p0[(size_t)grow * OUT_CH + col] = f2b(dinv[grow] * v);
            }
        }
    }
}

// ---------------- propagation: 16 lanes/node, pad8 CSR, LDS-staged gathers ----------------
// p layout: u32[node][16], element l = channels (2l | 2l+1<<16); row N_NODES is all-zero.
// R13 lesson: 8-deep and 16-deep VGPR-held gathers both 55.6us/step -> depth x waves
// trades off through VGPRs; chip-wide outstanding requests constant. Fix: stage gathers
// via global_load_lds (ZERO dest VGPRs; HW writes base+lane*4 = exactly our layout, each
// lane reads back its own word). VGPR ~35 -> 8 waves/SIMD; LDS 16KB -> 8 blocks/CU
// resident -> ~2x outstanding requests. NO min-waves launch bound (R8 lesson).

__global__ __launch_bounds__(256) void k_prop(const u32* __restrict__ pin, u32* __restrict__ pout,
                                              float* __restrict__ hout, const float* __restrict__ h0,
                                              const int* __restrict__ off, const int* __restrict__ csr_row,
                                              const float* __restrict__ dinv, int last) {
    __shared__ __align__(16) u32 stage[4][16][64];   // [wave][slot][lane] = 16KB
    int t = threadIdx.x;
    int wv = t >> 6, ln = t & 63;
    int gw = blockIdx.x * 16 + (t >> 4);     // node (grid = N/16 blocks, N%16==0)
    int l = t & 15;
    int lbase = t & 48;
    int s = off[gw], e = off[gw + 1];        // (e-s) % 8 == 0 by construction
    float dv = dinv[gw];
    u32 selfp = pin[(size_t)gw * 16 + l];
    float2 h0v = ((const float2*)h0)[(size_t)gw * 16 + l];

    float acc0 = 0.f, acc1 = 0.f;
    int base = s;
    // main loop: 16 edges per iter, 16 async gathers in flight, no dest VGPRs
    for (; base + 16 <= e; base += 16) {
        int idx = csr_row[base + l];          // 16 distinct indices, 64B coalesced per group
        asm volatile("s_waitcnt lgkmcnt(0)" ::: "memory");   // prior slot reads done before rewrite
        #pragma unroll
        for (int i = 0; i < 16; ++i) {
            int r = __shfl(idx, lbase + i, 64);
            load_lds4(pin + (size_t)r * 16 + l, &stage[wv][i][0]);  // lane ln -> stage[wv][i][ln]
        }
        asm volatile("s_waitcnt vmcnt(0)" ::: "memory");
        #pragma unroll
        for (int i = 0; i < 16; ++i) {
            u32 v = stage[wv][i][ln];
            union { u32 u; float f; } a, b;
            a.u = v << 16; b.u = v & 0xffff0000u;
            acc0 += a.f; acc1 += b.f;
        }
    }
    if (base < e) {   // 8-edge tail (pad8 guarantees exactly one)
        int idx = csr_row[base + (l & 7)];    // lanes 8-15 duplicate 0-7 (broadcast-coalesced)
        asm volatile("s_waitcnt lgkmcnt(0)" ::: "memory");
        #pragma unroll
        for (int i = 0; i < 8; ++i) {
            int r = __shfl(idx, lbase + i, 64);
            load_lds4(pin + (size_t)r * 16 + l, &stage[wv][i][0]);
        }
        asm volatile("s_waitcnt vmcnt(0)" ::: "memory");
        #pragma unroll
        for (int i = 0; i < 8; ++i) {
            u32 v = stage[wv][i][ln];
            union { u32 u; float f; } a, b;
            a.u = v << 16; b.u = v & 0xffff0000u;
            acc0 += a.f; acc1 += b.f;
        }
    }
    acc0 += b2f((u16)selfp);
    acc1 += b2f((u16)(selfp >> 16));
    float hc0 = 0.9f * dv * acc0 + 0.1f * h0v.x;
    float hc1 = 0.9f * dv * acc1 + 0.1f * h0v.y;
    if (last) {
        ((float2*)hout)[(size_t)gw * 16 + l] = make_float2(hc0, hc1);
    } else {
        pout[(size_t)gw * 16 + l] = (u32)f2b(dv * hc0) | ((u32)f2b(dv * hc1) << 16);
    }
}

// ---------------- launch ----------------

extern "C" void kernel_launch(void* const* d_in, const int* in_sizes, int n_in,
                              void* d_out, int out_size, void* d_ws, size_t ws_size,
                              hipStream_t stream) {
    const float* x  = (const float*)d_in[0];
    const int*   ei = (const int*)d_in[1];      // [2][E]
    const float* W1 = (const float*)d_in[2];
    const float* b1 = (const float*)d_in[3];
    const float* Wr = (const float*)d_in[4];
    const float* br = (const float*)d_in[5];
    const float* W2 = (const float*)d_in[6];
    const float* b2 = (const float*)d_in[7];
    float* out = (float*)d_out;

    char* ws = (char*)d_ws;
    size_t off_b = 0;
    auto take = [&](size_t bytes) {
        void* p = ws + off_b;
        off_b += (bytes + 255) & ~(size_t)255;
        return p;
    };

    float* h0      = (float*)take((size_t)N_NODES * OUT_CH * 4);
    u16*   pA      = (u16*)  take((size_t)(N_NODES + 1) * OUT_CH * 2);
    u16*   pB      = (u16*)  take((size_t)(N_NODES + 1) * OUT_CH * 2);
    int*   csr_row = (int*)  take((size_t)EPAD * 4);
    float* dinv    = (float*)take((size_t)N_NODES * 4);
    int*   cnt     = (int*)  take((size_t)N_NODES * 4);
    int*   offs    = (int*)  take((size_t)(N_NODES + 1) * 4);
    int*   cursor  = (int*)  take((size_t)N_NODES * 4);
    int*   bs      = (int*)  take(1024);
    int*   bo      = (int*)  take(1024);
    u16*   W1b     = (u16*)  take((size_t)HID * IN_CH * 2);
    u16*   Wrb     = (u16*)  take((size_t)HID * HID * 2);

    const int* e_row = ei;
    const int* e_col = ei + E_EDGES;

    // 1) weight casts
    k_cast<<<(HID * IN_CH / 4 + 255) / 256, 256, 0, stream>>>(W1, W1b, HID * IN_CH / 4);
    k_cast<<<(HID * HID / 4 + 255) / 256, 256, 0, stream>>>(Wr, Wrb, HID * HID / 4);

    // 2) preprocessing (degree -> dinv must precede fused MLP; pad8 CSR for prop)
    hipMemsetAsync(cnt, 0, (size_t)N_NODES * 4, stream);
    hipMemsetAsync(cursor, 0, (size_t)N_NODES * 4, stream);
    hipMemsetAsync(pA + (size_t)N_NODES * OUT_CH, 0, OUT_CH * 2, stream);  // zero dummy row
    hipMemsetAsync(pB + (size_t)N_NODES * OUT_CH, 0, OUT_CH * 2, stream);
    const int NB = (N_NODES + 1023) / 1024;  // 98
    k_count<<<(E_EDGES + 255) / 256, 256, 0, stream>>>(e_col, cnt);
    k_dinv<<<(N_NODES + 255) / 256, 256, 0, stream>>>(cnt, dinv);
    k_blocksum<<<NB, 256, 0, stream>>>(cnt, bs);
    k_scanblocks<<<1, 128, 0, stream>>>(bs, bo, NB);
    k_scanwithin<<<NB, 256, 0, stream>>>(cnt, bo, offs);
    k_total<<<1, 1, 0, stream>>>(bo, bs, offs, NB);
    k_filldummy<<<(EPAD + 255) / 256, 256, 0, stream>>>(csr_row);
    k_fill<<<(E_EDGES + 255) / 256, 256, 0, stream>>>(e_row, e_col, offs, cursor, csr_row);

    // 3) fused MLP: x -> h1 -> xres -> h0, p0 (one pass over x; intermediates in LDS)
    fused_mlp<<<(N_NODES + 63) / 64, 512, 0, stream>>>(x, W1b, b1, Wrb, br, W2, b2,
                                                       dinv, h0, pA, N_NODES);

    // 4) propagation: K steps on packed bf16 p, final step writes fp32 h to out
    const u32* pin = (const u32*)pA;
    for (int s = 0; s < K_STEPS; ++s) {
        int last = (s == K_STEPS - 1);
        u32* pout = (u32*)((s & 1) ? pA : pB);
        k_prop<<<N_NODES / 16, 256, 0, stream>>>(pin, pout, out, h0, offs, csr_row, dinv, last);
        pin = pout;
    }
}

// Round 16
// 746.611 us; speedup vs baseline: 7.0263x; 1.0196x over previous
//
#include <hip/hip_runtime.h>

#define N_NODES 100000
#define E_EDGES 1600000
#define IN_CH   512
#define HID     256
#define OUT_CH  32
#define K_STEPS 10
#define EPAD    (E_EDGES + 8 * N_NODES)   // worst-case pad8 CSR length

typedef unsigned short u16;
typedef unsigned int   u32;

typedef __attribute__((ext_vector_type(8))) short bf16x8;
typedef __attribute__((ext_vector_type(4))) float f32x4;

__device__ __forceinline__ float b2f(u16 u) {
    union { u32 i; float f; } x; x.i = ((u32)u) << 16; return x.f;
}
__device__ __forceinline__ u16 f2b(float f) {
    union { float f; u32 u; } x; x.f = f;
    u32 r = x.u + 0x7fffu + ((x.u >> 16) & 1u);
    return (u16)(r >> 16);
}

// async global->LDS. LDS dest is wave-uniform base + lane*size; global src is per-lane.
__device__ __forceinline__ void load_lds16(const void* g, void* l) {
    __builtin_amdgcn_global_load_lds(
        (const __attribute__((address_space(1))) unsigned int*)g,
        (__attribute__((address_space(3))) unsigned int*)l,
        16, 0, 0);
}
__device__ __forceinline__ void load_lds4(const void* g, void* l) {
    __builtin_amdgcn_global_load_lds(
        (const __attribute__((address_space(1))) unsigned int*)g,
        (__attribute__((address_space(3))) unsigned int*)l,
        4, 0, 0);
}

// ---------------- casts (weights only) ----------------

__global__ __launch_bounds__(256) void k_cast(const float* __restrict__ in, u16* __restrict__ out, int n4) {
    int i = blockIdx.x * 256 + threadIdx.x;
    if (i < n4) {
        float4 f = ((const float4*)in)[i];
        ushort4 u;
        u.x = f2b(f.x); u.y = f2b(f.y); u.z = f2b(f.z); u.w = f2b(f.w);
        ((ushort4*)out)[i] = u;
    }
}

// ---------------- preprocessing: degree, dinv, padded scan, CSR fill ----------------

__global__ __launch_bounds__(256) void k_count(const int* __restrict__ col, int* __restrict__ cnt) {
    int i = blockIdx.x * 256 + threadIdx.x;
    if (i < E_EDGES) atomicAdd(&cnt[col[i]], 1);
}

__global__ __launch_bounds__(256) void k_dinv(const int* __restrict__ cnt, float* __restrict__ dinv) {
    int i = blockIdx.x * 256 + threadIdx.x;
    if (i < N_NODES) dinv[i] = rsqrtf((float)(cnt[i] + 1));  // +1 self-loop
}

__device__ __forceinline__ int pad8(int v) { return (v + 7) & ~7; }

__global__ __launch_bounds__(256) void k_blocksum(const int* __restrict__ cnt, int* __restrict__ bs) {
    int b = blockIdx.x, t = threadIdx.x;
    int idx = b * 1024 + t * 4;
    int s = 0;
    #pragma unroll
    for (int j = 0; j < 4; ++j) if (idx + j < N_NODES) s += pad8(cnt[idx + j]);
    #pragma unroll
    for (int d = 32; d > 0; d >>= 1) s += __shfl_down(s, d, 64);
    __shared__ int smem[4];
    int lane = t & 63, w = t >> 6;
    if (lane == 0) smem[w] = s;
    __syncthreads();
    if (t == 0) bs[b] = smem[0] + smem[1] + smem[2] + smem[3];
}

__global__ void k_scanblocks(const int* __restrict__ bs, int* __restrict__ bo, int nb) {
    int t = threadIdx.x;  // 128 threads, nb <= 128
    int v = (t < nb) ? bs[t] : 0;
    int incl = v;
    int lane = t & 63, w = t >> 6;
    #pragma unroll
    for (int d = 1; d < 64; d <<= 1) { int tt = __shfl_up(incl, d, 64); if (lane >= d) incl += tt; }
    __shared__ int wsum[2];
    if (lane == 63) wsum[w] = incl;
    __syncthreads();
    int add = (w == 1) ? wsum[0] : 0;
    if (t < nb) bo[t] = add + incl - v;  // exclusive
}

__global__ __launch_bounds__(256) void k_scanwithin(const int* __restrict__ cnt, const int* __restrict__ bo,
                                                    int* __restrict__ off) {
    int b = blockIdx.x, t = threadIdx.x;
    int idx = b * 1024 + t * 4;
    int v[4]; int s = 0;
    #pragma unroll
    for (int j = 0; j < 4; ++j) { v[j] = (idx + j < N_NODES) ? pad8(cnt[idx + j]) : 0; s += v[j]; }
    int incl = s;
    int lane = t & 63, w = t >> 6;
    #pragma unroll
    for (int d = 1; d < 64; d <<= 1) { int tt = __shfl_up(incl, d, 64); if (lane >= d) incl += tt; }
    __shared__ int wsum[4];
    if (lane == 63) wsum[w] = incl;
    __syncthreads();
    int woff = 0;
    #pragma unroll
    for (int k = 0; k < 4; ++k) if (k < w) woff += wsum[k];
    int run = bo[b] + woff + incl - s;
    #pragma unroll
    for (int j = 0; j < 4; ++j) { if (idx + j < N_NODES) off[idx + j] = run; run += v[j]; }
}

__global__ __launch_bounds__(256) void k_total(const int* __restrict__ bo, const int* __restrict__ bs,
                                               int* __restrict__ off, int nb) {
    off[N_NODES] = bo[nb - 1] + bs[nb - 1];
}

// prefill padded CSR with the dummy node index (p[N] == 0 always)
__global__ __launch_bounds__(256) void k_filldummy(int* __restrict__ csr_row) {
    int i = blockIdx.x * 256 + threadIdx.x;
    if (i < EPAD) csr_row[i] = N_NODES;
}

__global__ __launch_bounds__(256) void k_fill(const int* __restrict__ row, const int* __restrict__ col,
                                              const int* __restrict__ off, int* __restrict__ cursor,
                                              int* __restrict__ csr_row) {
    int i = blockIdx.x * 256 + threadIdx.x;
    if (i < E_EDGES) {
        int c = col[i];
        int pos = off[c] + atomicAdd(&cursor[c], 1);
        csr_row[pos] = row[i];
    }
}

// ---------------- fused MLP: h1 = relu(xW1^T+b1); xres = h1 + relu(h1 Wr^T+br);
// ----------------            h0 = xres W2^T + b2; p0 = bf16(dinv .* h0)
// One block = 64 rows x full 256 hidden channels. 512 threads (8 waves, 2x4, 32x64/wave).
// launch_bounds (512,4): MEASURED best (R2/R15: 149-153us, VGPR=64, occ 38%).
// (512,2) measured WORSE (R13: 170us). R16 change: depth-2 x-prefetch in phase A —
// writeA(it+1) consumes a load issued at it-1 (full-iteration latency cover vs
// same-iteration consume which exposed ~700cy HBM latency per K-step).

// u16-element index into a [rows][256] bf16 LDS tile with 16B-chunk XOR swizzle
__device__ __forceinline__ int swz_idx(int row, int col) {
    return row * 256 + (((col >> 3) ^ (row & 7)) << 3) + (col & 7);
}

__global__ __launch_bounds__(512, 4) void fused_mlp(const float* __restrict__ A,      // x [M][512] fp32
                                                    const u16* __restrict__ W1b,      // [256][512] bf16
                                                    const float* __restrict__ b1,
                                                    const u16* __restrict__ Wrb,      // [256][256] bf16
                                                    const float* __restrict__ br,
                                                    const float* __restrict__ W2,     // [32][256] fp32
                                                    const float* __restrict__ b2,
                                                    const float* __restrict__ dinv,
                                                    float* __restrict__ h0,           // [M][32] fp32
                                                    u16* __restrict__ p0,             // [M][32] bf16
                                                    int M) {
    __shared__ __align__(16) u16 h1s[64 * 256];       // 32KB: h1, then xres (in place)
    __shared__ __align__(16) u16 Bs2[2][256 * 32];    // 32KB: W1b/Wrb K-tiles
    __shared__ __align__(16) u16 As2[2][64 * 32];     // 8KB:  x K-tiles
    u16* W2s = &Bs2[0][0];                            // [32][256] bf16 swizzled; Bs2[0] dead in phase C

    const int t = threadIdx.x;
    const int lane = t & 63, w = t >> 6;              // 8 waves
    const int wr = (w >> 2) * 32;                     // 0 / 32
    const int wc = (w & 3) * 64;                      // 0 / 64 / 128 / 192
    const int rr = lane >> 2, cc = lane & 3;
    const int fr = lane & 15, quad = lane >> 4;
    const int row0 = blockIdx.x * 64;

    f32x4 acc[2][4] = {};
    const int arow = t >> 3, aseg = t & 7;            // 64 rows x 8 float4 segs

    auto loadx = [&](int k0) -> float4 {
        int gr = row0 + arow; if (gr > M - 1) gr = M - 1;
        return *(const float4*)&A[(size_t)gr * IN_CH + k0 + aseg * 4];
    };
    auto writex = [&](int b, float4 f) {
        u32 lo = (u32)f2b(f.x) | ((u32)f2b(f.y) << 16);
        u32 hi = (u32)f2b(f.z) | ((u32)f2b(f.w) << 16);
        *(uint2*)&As2[b][arow * 32 + aseg * 4] = make_uint2(lo, hi);
    };
    auto loadB1 = [&](int k0, int b) {   // W1b tile [256][32]
        #pragma unroll
        for (int rep = 0; rep < 2; ++rep) {
            int ii = w * 2 + rep;                       // 0..15
            int gc = ii * 16 + rr;                      // 0..255
            load_lds16(W1b + (size_t)gc * IN_CH + k0 + cc * 8, &Bs2[b][ii * 512]);
        }
    };
    auto loadB2 = [&](int k0, int b) {   // Wrb tile [256][32]
        #pragma unroll
        for (int rep = 0; rep < 2; ++rep) {
            int ii = w * 2 + rep;
            int gc = ii * 16 + rr;
            load_lds16(Wrb + (size_t)gc * HID + k0 + cc * 8, &Bs2[b][ii * 512]);
        }
    };
    auto mfmaStepA = [&](int cur) {
        bf16x8 af[2], bfr[4];
        #pragma unroll
        for (int ti = 0; ti < 2; ++ti)
            af[ti] = *(const bf16x8*)&As2[cur][(wr + ti * 16 + fr) * 32 + quad * 8];
        #pragma unroll
        for (int tj = 0; tj < 4; ++tj)
            bfr[tj] = *(const bf16x8*)&Bs2[cur][(wc + tj * 16 + fr) * 32 + quad * 8];
        #pragma unroll
        for (int ti = 0; ti < 2; ++ti)
            #pragma unroll
            for (int tj = 0; tj < 4; ++tj)
                acc[ti][tj] = __builtin_amdgcn_mfma_f32_16x16x32_bf16(af[ti], bfr[tj], acc[ti][tj], 0, 0, 0);
    };

    // ---------- Phase A: h1 = relu(x @ W1^T + b1), K = 512, depth-2 x prefetch ----------
    float4 fpA = loadx(0);
    loadB1(0, 0);
    writex(0, fpA);
    float4 fpB = loadx(32);
    __syncthreads();

    #pragma unroll
    for (int base_it = 0; base_it < IN_CH / 32; base_it += 2) {
        {   // even iteration: tile base_it in As2[0]; consume fpB (tile it+1), refill fpA (tile it+2)
            const int it = base_it;
            if (it + 2 < IN_CH / 32) fpA = loadx((it + 2) * 32);
            mfmaStepA(0);
            if (it + 1 < IN_CH / 32) {
                loadB1((it + 1) * 32, 1);
                writex(1, fpB);
                __syncthreads();
            }
        }
        {   // odd iteration: tile base_it+1 in As2[1]; consume fpA, refill fpB
            const int it = base_it + 1;
            if (it + 2 < IN_CH / 32) fpB = loadx((it + 2) * 32);
            mfmaStepA(1);
            if (it + 1 < IN_CH / 32) {
                loadB1((it + 1) * 32, 0);
                writex(0, fpA);
                __syncthreads();
            }
        }
    }

    // epilogue A: relu+bias -> h1s (swizzled). Prefetch Wrb k0=0 concurrently.
    loadB2(0, 0);
    #pragma unroll
    for (int tj = 0; tj < 4; ++tj) {
        int col = wc + tj * 16 + fr;
        float bv = b1[col];
        #pragma unroll
        for (int ti = 0; ti < 2; ++ti)
            #pragma unroll
            for (int r = 0; r < 4; ++r) {
                int row = wr + ti * 16 + quad * 4 + r;
                h1s[swz_idx(row, col)] = f2b(fmaxf(acc[ti][tj][r] + bv, 0.f));
            }
    }
    __syncthreads();   // drains Wrb async load + h1 ds_writes

    // ---------- Phase B: h2 = relu(h1 @ Wr^T + br), K = 256; A-frags from h1s ----------
    #pragma unroll
    for (int ti = 0; ti < 2; ++ti)
        #pragma unroll
        for (int tj = 0; tj < 4; ++tj)
            #pragma unroll
            for (int r = 0; r < 4; ++r) acc[ti][tj][r] = 0.f;

    for (int it = 0; it < HID / 32; ++it) {
        const int cur = it & 1;
        const bool more = (it < HID / 32 - 1);
        if (more) loadB2((it + 1) * 32, cur ^ 1);
        bf16x8 af[2], bfr[4];
        #pragma unroll
        for (int ti = 0; ti < 2; ++ti) {
            int row = wr + ti * 16 + fr;
            af[ti] = *(const bf16x8*)&h1s[row * 256 + (((it * 4 + quad) ^ (row & 7)) << 3)];
        }
        #pragma unroll
        for (int tj = 0; tj < 4; ++tj)
            bfr[tj] = *(const bf16x8*)&Bs2[cur][(wc + tj * 16 + fr) * 32 + quad * 8];
        #pragma unroll
        for (int ti = 0; ti < 2; ++ti)
            #pragma unroll
            for (int tj = 0; tj < 4; ++tj)
                acc[ti][tj] = __builtin_amdgcn_mfma_f32_16x16x32_bf16(af[ti], bfr[tj], acc[ti][tj], 0, 0, 0);
        if (more) __syncthreads();
    }
    __syncthreads();   // all h1s frag reads + Bs2[0] reads complete

    // epilogue B: xres = h1 + relu(h2) (in place); stage W2 -> W2s (aliases dead Bs2[0])
    float4 wf[4];
    const int wrow = t >> 4, wseg = t & 15;           // 32 x 16 = 512 threads
    {
        const float* src = W2 + (size_t)wrow * HID + wseg * 16;
        wf[0] = *(const float4*)(src + 0);
        wf[1] = *(const float4*)(src + 4);
        wf[2] = *(const float4*)(src + 8);
        wf[3] = *(const float4*)(src + 12);
    }
    #pragma unroll
    for (int tj = 0; tj < 4; ++tj) {
        int col = wc + tj * 16 + fr;
        float bv = br[col];
        #pragma unroll
        for (int ti = 0; ti < 2; ++ti)
            #pragma unroll
            for (int r = 0; r < 4; ++r) {
                int row = wr + ti * 16 + quad * 4 + r;
                int idx = swz_idx(row, col);
                float h1v = b2f(h1s[idx]);
                h1s[idx] = f2b(h1v + fmaxf(acc[ti][tj][r] + bv, 0.f));
            }
    }
    {
        union { u16 s[8]; uint4 q; } pk;
        #pragma unroll
        for (int half = 0; half < 2; ++half) {
            float4 a = wf[half * 2], b = wf[half * 2 + 1];
            pk.s[0] = f2b(a.x); pk.s[1] = f2b(a.y); pk.s[2] = f2b(a.z); pk.s[3] = f2b(a.w);
            pk.s[4] = f2b(b.x); pk.s[5] = f2b(b.y); pk.s[6] = f2b(b.z); pk.s[7] = f2b(b.w);
            int chunk = wseg * 2 + half;
            *(uint4*)&W2s[wrow * 256 + ((chunk ^ (wrow & 7)) << 3)] = pk.q;
        }
    }
    __syncthreads();   // xres + W2s visible

    // ---------- Phase C: h0 = xres @ W2^T + b2 (K=256, N=32) ----------
    // wave w -> rows (w>>1)*16..+15, cols (w&1)*16..+15
    f32x4 acc3;
    #pragma unroll
    for (int r = 0; r < 4; ++r) acc3[r] = 0.f;

    const int crow = (w >> 1) * 16, ccol = (w & 1) * 16;
    for (int it = 0; it < HID / 32; ++it) {
        int ar = crow + fr;
        bf16x8 af = *(const bf16x8*)&h1s[ar * 256 + (((it * 4 + quad) ^ (ar & 7)) << 3)];
        int bc = ccol + fr;
        bf16x8 bfr = *(const bf16x8*)&W2s[bc * 256 + (((it * 4 + quad) ^ (bc & 7)) << 3)];
        acc3 = __builtin_amdgcn_mfma_f32_16x16x32_bf16(af, bfr, acc3, 0, 0, 0);
    }

    {
        int col = ccol + fr;
        float bv = b2[col];
        #pragma unroll
        for (int r = 0; r < 4; ++r) {
            int grow = row0 + crow + quad * 4 + r;
            if (grow < M) {
                float v = acc3[r] + bv;
                h0[(size_t)grow * OUT_CH + col] = v;
                p0[(size_t)grow * OUT_CH + col] = f2b(dinv[grow] * v);
            }
        }
    }
}

// ---------------- propagation: 16 lanes/node, pad8 CSR, LDS-staged gathers ----------------
// p layout: u32[node][16], element l = channels (2l | 2l+1<<16); row N_NODES is all-zero.
// STRUCTURE-PINNED at 55.6-55.8us/step: invariant across {depth 8/16, VGPR/LDS dest,
// +-17% request count, explicit/compiler waitcnt} (R1/R2/R13/R15). ~36G random-64B-req/s
// hardware floor. fp8 shrink blocked: absmax already at threshold. DO NOT TOUCH.

__global__ __launch_bounds__(256) void k_prop(const u32* __restrict__ pin, u32* __restrict__ pout,
                                              float* __restrict__ hout, const float* __restrict__ h0,
                                              const int* __restrict__ off, const int* __restrict__ csr_row,
                                              const float* __restrict__ dinv, int last) {
    __shared__ __align__(16) u32 stage[4][16][64];   // [wave][slot][lane] = 16KB
    int t = threadIdx.x;
    int wv = t >> 6, ln = t & 63;
    int gw = blockIdx.x * 16 + (t >> 4);     // node (grid = N/16 blocks, N%16==0)
    int l = t & 15;
    int lbase = t & 48;
    int s = off[gw], e = off[gw + 1];        // (e-s) % 8 == 0 by construction
    float dv = dinv[gw];
    u32 selfp = pin[(size_t)gw * 16 + l];
    float2 h0v = ((const float2*)h0)[(size_t)gw * 16 + l];

    float acc0 = 0.f, acc1 = 0.f;
    int base = s;
    // main loop: 16 edges per iter, 16 async gathers in flight, no dest VGPRs
    for (; base + 16 <= e; base += 16) {
        int idx = csr_row[base + l];          // 16 distinct indices, 64B coalesced per group
        asm volatile("s_waitcnt lgkmcnt(0)" ::: "memory");   // prior slot reads done before rewrite
        #pragma unroll
        for (int i = 0; i < 16; ++i) {
            int r = __shfl(idx, lbase + i, 64);
            load_lds4(pin + (size_t)r * 16 + l, &stage[wv][i][0]);  // lane ln -> stage[wv][i][ln]
        }
        asm volatile("s_waitcnt vmcnt(0)" ::: "memory");
        #pragma unroll
        for (int i = 0; i < 16; ++i) {
            u32 v = stage[wv][i][ln];
            union { u32 u; float f; } a, b;
            a.u = v << 16; b.u = v & 0xffff0000u;
            acc0 += a.f; acc1 += b.f;
        }
    }
    if (base < e) {   // 8-edge tail (pad8 guarantees exactly one)
        int idx = csr_row[base + (l & 7)];    // lanes 8-15 duplicate 0-7 (broadcast-coalesced)
        asm volatile("s_waitcnt lgkmcnt(0)" ::: "memory");
        #pragma unroll
        for (int i = 0; i < 8; ++i) {
            int r = __shfl(idx, lbase + i, 64);
            load_lds4(pin + (size_t)r * 16 + l, &stage[wv][i][0]);
        }
        asm volatile("s_waitcnt vmcnt(0)" ::: "memory");
        #pragma unroll
        for (int i = 0; i < 8; ++i) {
            u32 v = stage[wv][i][ln];
            union { u32 u; float f; } a, b;
            a.u = v << 16; b.u = v & 0xffff0000u;
            acc0 += a.f; acc1 += b.f;
        }
    }
    acc0 += b2f((u16)selfp);
    acc1 += b2f((u16)(selfp >> 16));
    float hc0 = 0.9f * dv * acc0 + 0.1f * h0v.x;
    float hc1 = 0.9f * dv * acc1 + 0.1f * h0v.y;
    if (last) {
        ((float2*)hout)[(size_t)gw * 16 + l] = make_float2(hc0, hc1);
    } else {
        pout[(size_t)gw * 16 + l] = (u32)f2b(dv * hc0) | ((u32)f2b(dv * hc1) << 16);
    }
}

// ---------------- launch ----------------

extern "C" void kernel_launch(void* const* d_in, const int* in_sizes, int n_in,
                              void* d_out, int out_size, void* d_ws, size_t ws_size,
                              hipStream_t stream) {
    const float* x  = (const float*)d_in[0];
    const int*   ei = (const int*)d_in[1];      // [2][E]
    const float* W1 = (const float*)d_in[2];
    const float* b1 = (const float*)d_in[3];
    const float* Wr = (const float*)d_in[4];
    const float* br = (const float*)d_in[5];
    const float* W2 = (const float*)d_in[6];
    const float* b2 = (const float*)d_in[7];
    float* out = (float*)d_out;

    char* ws = (char*)d_ws;
    size_t off_b = 0;
    auto take = [&](size_t bytes) {
        void* p = ws + off_b;
        off_b += (bytes + 255) & ~(size_t)255;
        return p;
    };

    float* h0      = (float*)take((size_t)N_NODES * OUT_CH * 4);
    u16*   pA      = (u16*)  take((size_t)(N_NODES + 1) * OUT_CH * 2);
    u16*   pB      = (u16*)  take((size_t)(N_NODES + 1) * OUT_CH * 2);
    int*   csr_row = (int*)  take((size_t)EPAD * 4);
    float* dinv    = (float*)take((size_t)N_NODES * 4);
    int*   cnt     = (int*)  take((size_t)N_NODES * 4);
    int*   offs    = (int*)  take((size_t)(N_NODES + 1) * 4);
    int*   cursor  = (int*)  take((size_t)N_NODES * 4);
    int*   bs      = (int*)  take(1024);
    int*   bo      = (int*)  take(1024);
    u16*   W1b     = (u16*)  take((size_t)HID * IN_CH * 2);
    u16*   Wrb     = (u16*)  take((size_t)HID * HID * 2);

    const int* e_row = ei;
    const int* e_col = ei + E_EDGES;

    // 1) weight casts
    k_cast<<<(HID * IN_CH / 4 + 255) / 256, 256, 0, stream>>>(W1, W1b, HID * IN_CH / 4);
    k_cast<<<(HID * HID / 4 + 255) / 256, 256, 0, stream>>>(Wr, Wrb, HID * HID / 4);

    // 2) preprocessing (degree -> dinv must precede fused MLP; pad8 CSR for prop)
    hipMemsetAsync(cnt, 0, (size_t)N_NODES * 4, stream);
    hipMemsetAsync(cursor, 0, (size_t)N_NODES * 4, stream);
    hipMemsetAsync(pA + (size_t)N_NODES * OUT_CH, 0, OUT_CH * 2, stream);  // zero dummy row
    hipMemsetAsync(pB + (size_t)N_NODES * OUT_CH, 0, OUT_CH * 2, stream);
    const int NB = (N_NODES + 1023) / 1024;  // 98
    k_count<<<(E_EDGES + 255) / 256, 256, 0, stream>>>(e_col, cnt);
    k_dinv<<<(N_NODES + 255) / 256, 256, 0, stream>>>(cnt, dinv);
    k_blocksum<<<NB, 256, 0, stream>>>(cnt, bs);
    k_scanblocks<<<1, 128, 0, stream>>>(bs, bo, NB);
    k_scanwithin<<<NB, 256, 0, stream>>>(cnt, bo, offs);
    k_total<<<1, 1, 0, stream>>>(bo, bs, offs, NB);
    k_filldummy<<<(EPAD + 255) / 256, 256, 0, stream>>>(csr_row);
    k_fill<<<(E_EDGES + 255) / 256, 256, 0, stream>>>(e_row, e_col, offs, cursor, csr_row);

    // 3) fused MLP: x -> h1 -> xres -> h0, p0 (one pass over x; intermediates in LDS)
    fused_mlp<<<(N_NODES + 63) / 64, 512, 0, stream>>>(x, W1b, b1, Wrb, br, W2, b2,
                                                       dinv, h0, pA, N_NODES);

    // 4) propagation: K steps on packed bf16 p, final step writes fp32 h to out
    const u32* pin = (const u32*)pA;
    for (int s = 0; s < K_STEPS; ++s) {
        int last = (s == K_STEPS - 1);
        u32* pout = (u32*)((s & 1) ? pA : pB);
        k_prop<<<N_NODES / 16, 256, 0, stream>>>(pin, pout, out, h0, offs, csr_row, dinv, last);
        pin = pout;
    }
}

// Round 17
// 739.751 us; speedup vs baseline: 7.0914x; 1.0093x over previous
//
#include <hip/hip_runtime.h>

#define N_NODES 100000
#define E_EDGES 1600000
#define IN_CH   512
#define HID     256
#define OUT_CH  32
#define K_STEPS 10
#define EPAD    (E_EDGES + 8 * N_NODES)   // worst-case pad8 CSR length

typedef unsigned short u16;
typedef unsigned int   u32;

typedef __attribute__((ext_vector_type(8))) short bf16x8;
typedef __attribute__((ext_vector_type(4))) float f32x4;

__device__ __forceinline__ float b2f(u16 u) {
    union { u32 i; float f; } x; x.i = ((u32)u) << 16; return x.f;
}
__device__ __forceinline__ u16 f2b(float f) {
    union { float f; u32 u; } x; x.f = f;
    u32 r = x.u + 0x7fffu + ((x.u >> 16) & 1u);
    return (u16)(r >> 16);
}

// async global->LDS. LDS dest is wave-uniform base + lane*size; global src is per-lane.
__device__ __forceinline__ void load_lds16(const void* g, void* l) {
    __builtin_amdgcn_global_load_lds(
        (const __attribute__((address_space(1))) unsigned int*)g,
        (__attribute__((address_space(3))) unsigned int*)l,
        16, 0, 0);
}
__device__ __forceinline__ void load_lds4(const void* g, void* l) {
    __builtin_amdgcn_global_load_lds(
        (const __attribute__((address_space(1))) unsigned int*)g,
        (__attribute__((address_space(3))) unsigned int*)l,
        4, 0, 0);
}

// ---------------- merged preprocessing (R17: dispatch-count reduction, 23 -> 17) ----------------

// both weight casts + zero the two dummy p-rows (one launch)
__global__ __launch_bounds__(256) void k_cast_all(const float* __restrict__ W1, const float* __restrict__ Wr,
                                                  u16* __restrict__ W1b, u16* __restrict__ Wrb,
                                                  u32* __restrict__ pAd, u32* __restrict__ pBd) {
    int i = blockIdx.x * 256 + threadIdx.x;
    const int n1 = HID * IN_CH / 4;        // 32768
    const int n2 = HID * HID / 4;          // 16384
    if (i < n1) {
        float4 f = ((const float4*)W1)[i];
        ushort4 u;
        u.x = f2b(f.x); u.y = f2b(f.y); u.z = f2b(f.z); u.w = f2b(f.w);
        ((ushort4*)W1b)[i] = u;
    } else if (i < n1 + n2) {
        int j = i - n1;
        float4 f = ((const float4*)Wr)[j];
        ushort4 u;
        u.x = f2b(f.x); u.y = f2b(f.y); u.z = f2b(f.z); u.w = f2b(f.w);
        ((ushort4*)Wrb)[j] = u;
    }
    if (blockIdx.x == 0) {
        if (threadIdx.x < 16) pAd[threadIdx.x] = 0;          // 64B dummy row pA
        else if (threadIdx.x < 32) pBd[threadIdx.x - 16] = 0; // 64B dummy row pB
    }
}

// degree count + prefill padded CSR with dummy index (independent writes, one launch)
__global__ __launch_bounds__(256) void k_count_filldummy(const int* __restrict__ col,
                                                         int* __restrict__ cnt,
                                                         int* __restrict__ csr_row) {
    int i = blockIdx.x * 256 + threadIdx.x;
    if (i < EPAD) csr_row[i] = N_NODES;
    if (i < E_EDGES) atomicAdd(&cnt[col[i]], 1);
}

__device__ __forceinline__ int pad8(int v) { return (v + 7) & ~7; }

// per-block pad8 sums + dinv (cnt already being read here)
__global__ __launch_bounds__(256) void k_blocksum(const int* __restrict__ cnt, int* __restrict__ bs,
                                                  float* __restrict__ dinv) {
    int b = blockIdx.x, t = threadIdx.x;
    int idx = b * 1024 + t * 4;
    int s = 0;
    #pragma unroll
    for (int j = 0; j < 4; ++j) {
        if (idx + j < N_NODES) {
            int c = cnt[idx + j];
            dinv[idx + j] = rsqrtf((float)(c + 1));  // +1 self-loop
            s += pad8(c);
        }
    }
    #pragma unroll
    for (int d = 32; d > 0; d >>= 1) s += __shfl_down(s, d, 64);
    __shared__ int smem[4];
    int lane = t & 63, w = t >> 6;
    if (lane == 0) smem[w] = s;
    __syncthreads();
    if (t == 0) bs[b] = smem[0] + smem[1] + smem[2] + smem[3];
}

__global__ void k_scanblocks(const int* __restrict__ bs, int* __restrict__ bo, int nb) {
    int t = threadIdx.x;  // 128 threads, nb <= 128
    int v = (t < nb) ? bs[t] : 0;
    int incl = v;
    int lane = t & 63, w = t >> 6;
    #pragma unroll
    for (int d = 1; d < 64; d <<= 1) { int tt = __shfl_up(incl, d, 64); if (lane >= d) incl += tt; }
    __shared__ int wsum[2];
    if (lane == 63) wsum[w] = incl;
    __syncthreads();
    int add = (w == 1) ? wsum[0] : 0;
    if (t < nb) bo[t] = add + incl - v;  // exclusive
}

// within-block scan + total (last block writes off[N_NODES])
__global__ __launch_bounds__(256) void k_scanwithin(const int* __restrict__ cnt, const int* __restrict__ bo,
                                                    const int* __restrict__ bs, int* __restrict__ off) {
    int b = blockIdx.x, t = threadIdx.x;
    int idx = b * 1024 + t * 4;
    int v[4]; int s = 0;
    #pragma unroll
    for (int j = 0; j < 4; ++j) { v[j] = (idx + j < N_NODES) ? pad8(cnt[idx + j]) : 0; s += v[j]; }
    int incl = s;
    int lane = t & 63, w = t >> 6;
    #pragma unroll
    for (int d = 1; d < 64; d <<= 1) { int tt = __shfl_up(incl, d, 64); if (lane >= d) incl += tt; }
    __shared__ int wsum[4];
    if (lane == 63) wsum[w] = incl;
    __syncthreads();
    int woff = 0;
    #pragma unroll
    for (int k = 0; k < 4; ++k) if (k < w) woff += wsum[k];
    int run = bo[b] + woff + incl - s;
    #pragma unroll
    for (int j = 0; j < 4; ++j) { if (idx + j < N_NODES) off[idx + j] = run; run += v[j]; }
    if (b == (int)gridDim.x - 1 && t == 0) off[N_NODES] = bo[b] + bs[b];
}

// CSR fill; cnt doubles as cursor via atomic decrement (slots [0,deg) distinct; dinv already consumed cnt)
__global__ __launch_bounds__(256) void k_fill(const int* __restrict__ row, const int* __restrict__ col,
                                              const int* __restrict__ off, int* __restrict__ cnt,
                                              int* __restrict__ csr_row) {
    int i = blockIdx.x * 256 + threadIdx.x;
    if (i < E_EDGES) {
        int c = col[i];
        int pos = off[c] + atomicAdd(&cnt[c], -1) - 1;
        csr_row[pos] = row[i];
    }
}

// ---------------- fused MLP: h1 = relu(xW1^T+b1); xres = h1 + relu(h1 Wr^T+br);
// ----------------            h0 = xres W2^T + b2; p0 = bf16(dinv .* h0)
// One block = 64 rows x full 256 hidden channels. 512 threads (8 waves, 2x4, 32x64/wave).
// launch_bounds (512,4): MEASURED best. R16 depth-2 x-prefetch: 152->133us, VGPR 60,
// spills gone (WRITE 62.5->18.75MB). (512,2) measured WORSE (R13: 170us).

// u16-element index into a [rows][256] bf16 LDS tile with 16B-chunk XOR swizzle
__device__ __forceinline__ int swz_idx(int row, int col) {
    return row * 256 + (((col >> 3) ^ (row & 7)) << 3) + (col & 7);
}

__global__ __launch_bounds__(512, 4) void fused_mlp(const float* __restrict__ A,      // x [M][512] fp32
                                                    const u16* __restrict__ W1b,      // [256][512] bf16
                                                    const float* __restrict__ b1,
                                                    const u16* __restrict__ Wrb,      // [256][256] bf16
                                                    const float* __restrict__ br,
                                                    const float* __restrict__ W2,     // [32][256] fp32
                                                    const float* __restrict__ b2,
                                                    const float* __restrict__ dinv,
                                                    float* __restrict__ h0,           // [M][32] fp32
                                                    u16* __restrict__ p0,             // [M][32] bf16
                                                    int M) {
    __shared__ __align__(16) u16 h1s[64 * 256];       // 32KB: h1, then xres (in place)
    __shared__ __align__(16) u16 Bs2[2][256 * 32];    // 32KB: W1b/Wrb K-tiles
    __shared__ __align__(16) u16 As2[2][64 * 32];     // 8KB:  x K-tiles
    u16* W2s = &Bs2[0][0];                            // [32][256] bf16 swizzled; Bs2[0] dead in phase C

    const int t = threadIdx.x;
    const int lane = t & 63, w = t >> 6;              // 8 waves
    const int wr = (w >> 2) * 32;                     // 0 / 32
    const int wc = (w & 3) * 64;                      // 0 / 64 / 128 / 192
    const int rr = lane >> 2, cc = lane & 3;
    const int fr = lane & 15, quad = lane >> 4;
    const int row0 = blockIdx.x * 64;

    f32x4 acc[2][4] = {};
    const int arow = t >> 3, aseg = t & 7;            // 64 rows x 8 float4 segs

    auto loadx = [&](int k0) -> float4 {
        int gr = row0 + arow; if (gr > M - 1) gr = M - 1;
        return *(const float4*)&A[(size_t)gr * IN_CH + k0 + aseg * 4];
    };
    auto writex = [&](int b, float4 f) {
        u32 lo = (u32)f2b(f.x) | ((u32)f2b(f.y) << 16);
        u32 hi = (u32)f2b(f.z) | ((u32)f2b(f.w) << 16);
        *(uint2*)&As2[b][arow * 32 + aseg * 4] = make_uint2(lo, hi);
    };
    auto loadB1 = [&](int k0, int b) {   // W1b tile [256][32]
        #pragma unroll
        for (int rep = 0; rep < 2; ++rep) {
            int ii = w * 2 + rep;                       // 0..15
            int gc = ii * 16 + rr;                      // 0..255
            load_lds16(W1b + (size_t)gc * IN_CH + k0 + cc * 8, &Bs2[b][ii * 512]);
        }
    };
    auto loadB2 = [&](int k0, int b) {   // Wrb tile [256][32]
        #pragma unroll
        for (int rep = 0; rep < 2; ++rep) {
            int ii = w * 2 + rep;
            int gc = ii * 16 + rr;
            load_lds16(Wrb + (size_t)gc * HID + k0 + cc * 8, &Bs2[b][ii * 512]);
        }
    };
    auto mfmaStepA = [&](int cur) {
        bf16x8 af[2], bfr[4];
        #pragma unroll
        for (int ti = 0; ti < 2; ++ti)
            af[ti] = *(const bf16x8*)&As2[cur][(wr + ti * 16 + fr) * 32 + quad * 8];
        #pragma unroll
        for (int tj = 0; tj < 4; ++tj)
            bfr[tj] = *(const bf16x8*)&Bs2[cur][(wc + tj * 16 + fr) * 32 + quad * 8];
        #pragma unroll
        for (int ti = 0; ti < 2; ++ti)
            #pragma unroll
            for (int tj = 0; tj < 4; ++tj)
                acc[ti][tj] = __builtin_amdgcn_mfma_f32_16x16x32_bf16(af[ti], bfr[tj], acc[ti][tj], 0, 0, 0);
    };

    // ---------- Phase A: h1 = relu(x @ W1^T + b1), K = 512, depth-2 x prefetch ----------
    float4 fpA = loadx(0);
    loadB1(0, 0);
    writex(0, fpA);
    float4 fpB = loadx(32);
    __syncthreads();

    #pragma unroll
    for (int base_it = 0; base_it < IN_CH / 32; base_it += 2) {
        {   // even iteration: tile base_it in As2[0]; consume fpB (tile it+1), refill fpA (tile it+2)
            const int it = base_it;
            if (it + 2 < IN_CH / 32) fpA = loadx((it + 2) * 32);
            mfmaStepA(0);
            if (it + 1 < IN_CH / 32) {
                loadB1((it + 1) * 32, 1);
                writex(1, fpB);
                __syncthreads();
            }
        }
        {   // odd iteration: tile base_it+1 in As2[1]; consume fpA, refill fpB
            const int it = base_it + 1;
            if (it + 2 < IN_CH / 32) fpB = loadx((it + 2) * 32);
            mfmaStepA(1);
            if (it + 1 < IN_CH / 32) {
                loadB1((it + 1) * 32, 0);
                writex(0, fpA);
                __syncthreads();
            }
        }
    }

    // epilogue A: relu+bias -> h1s (swizzled). Prefetch Wrb k0=0 concurrently.
    loadB2(0, 0);
    #pragma unroll
    for (int tj = 0; tj < 4; ++tj) {
        int col = wc + tj * 16 + fr;
        float bv = b1[col];
        #pragma unroll
        for (int ti = 0; ti < 2; ++ti)
            #pragma unroll
            for (int r = 0; r < 4; ++r) {
                int row = wr + ti * 16 + quad * 4 + r;
                h1s[swz_idx(row, col)] = f2b(fmaxf(acc[ti][tj][r] + bv, 0.f));
            }
    }
    __syncthreads();   // drains Wrb async load + h1 ds_writes

    // ---------- Phase B: h2 = relu(h1 @ Wr^T + br), K = 256; A-frags from h1s ----------
    #pragma unroll
    for (int ti = 0; ti < 2; ++ti)
        #pragma unroll
        for (int tj = 0; tj < 4; ++tj)
            #pragma unroll
            for (int r = 0; r < 4; ++r) acc[ti][tj][r] = 0.f;

    for (int it = 0; it < HID / 32; ++it) {
        const int cur = it & 1;
        const bool more = (it < HID / 32 - 1);
        if (more) loadB2((it + 1) * 32, cur ^ 1);
        bf16x8 af[2], bfr[4];
        #pragma unroll
        for (int ti = 0; ti < 2; ++ti) {
            int row = wr + ti * 16 + fr;
            af[ti] = *(const bf16x8*)&h1s[row * 256 + (((it * 4 + quad) ^ (row & 7)) << 3)];
        }
        #pragma unroll
        for (int tj = 0; tj < 4; ++tj)
            bfr[tj] = *(const bf16x8*)&Bs2[cur][(wc + tj * 16 + fr) * 32 + quad * 8];
        #pragma unroll
        for (int ti = 0; ti < 2; ++ti)
            #pragma unroll
            for (int tj = 0; tj < 4; ++tj)
                acc[ti][tj] = __builtin_amdgcn_mfma_f32_16x16x32_bf16(af[ti], bfr[tj], acc[ti][tj], 0, 0, 0);
        if (more) __syncthreads();
    }
    __syncthreads();   // all h1s frag reads + Bs2[0] reads complete

    // epilogue B: xres = h1 + relu(h2) (in place); stage W2 -> W2s (aliases dead Bs2[0])
    float4 wf[4];
    const int wrow = t >> 4, wseg = t & 15;           // 32 x 16 = 512 threads
    {
        const float* src = W2 + (size_t)wrow * HID + wseg * 16;
        wf[0] = *(const float4*)(src + 0);
        wf[1] = *(const float4*)(src + 4);
        wf[2] = *(const float4*)(src + 8);
        wf[3] = *(const float4*)(src + 12);
    }
    #pragma unroll
    for (int tj = 0; tj < 4; ++tj) {
        int col = wc + tj * 16 + fr;
        float bv = br[col];
        #pragma unroll
        for (int ti = 0; ti < 2; ++ti)
            #pragma unroll
            for (int r = 0; r < 4; ++r) {
                int row = wr + ti * 16 + quad * 4 + r;
                int idx = swz_idx(row, col);
                float h1v = b2f(h1s[idx]);
                h1s[idx] = f2b(h1v + fmaxf(acc[ti][tj][r] + bv, 0.f));
            }
    }
    {
        union { u16 s[8]; uint4 q; } pk;
        #pragma unroll
        for (int half = 0; half < 2; ++half) {
            float4 a = wf[half * 2], b = wf[half * 2 + 1];
            pk.s[0] = f2b(a.x); pk.s[1] = f2b(a.y); pk.s[2] = f2b(a.z); pk.s[3] = f2b(a.w);
            pk.s[4] = f2b(b.x); pk.s[5] = f2b(b.y); pk.s[6] = f2b(b.z); pk.s[7] = f2b(b.w);
            int chunk = wseg * 2 + half;
            *(uint4*)&W2s[wrow * 256 + ((chunk ^ (wrow & 7)) << 3)] = pk.q;
        }
    }
    __syncthreads();   // xres + W2s visible

    // ---------- Phase C: h0 = xres @ W2^T + b2 (K=256, N=32) ----------
    // wave w -> rows (w>>1)*16..+15, cols (w&1)*16..+15
    f32x4 acc3;
    #pragma unroll
    for (int r = 0; r < 4; ++r) acc3[r] = 0.f;

    const int crow = (w >> 1) * 16, ccol = (w & 1) * 16;
    for (int it = 0; it < HID / 32; ++it) {
        int ar = crow + fr;
        bf16x8 af = *(const bf16x8*)&h1s[ar * 256 + (((it * 4 + quad) ^ (ar & 7)) << 3)];
        int bc = ccol + fr;
        bf16x8 bfr = *(const bf16x8*)&W2s[bc * 256 + (((it * 4 + quad) ^ (bc & 7)) << 3)];
        acc3 = __builtin_amdgcn_mfma_f32_16x16x32_bf16(af, bfr, acc3, 0, 0, 0);
    }

    {
        int col = ccol + fr;
        float bv = b2[col];
        #pragma unroll
        for (int r = 0; r < 4; ++r) {
            int grow = row0 + crow + quad * 4 + r;
            if (grow < M) {
                float v = acc3[r] + bv;
                h0[(size_t)grow * OUT_CH + col] = v;
                p0[(size_t)grow * OUT_CH + col] = f2b(dinv[grow] * v);
            }
        }
    }
}

// ---------------- propagation: 16 lanes/node, pad8 CSR, LDS-staged gathers ----------------
// p layout: u32[node][16], element l = channels (2l | 2l+1<<16); row N_NODES is all-zero.
// STRUCTURE-PINNED at 55.6-55.8us/step: invariant across {depth 8/16, VGPR/LDS dest,
// +-17% request count, explicit/compiler waitcnt} (R1/R2/R13/R15). ~36G random-64B-req/s
// hardware floor. fp8 shrink blocked: absmax already at threshold. DO NOT TOUCH.

__global__ __launch_bounds__(256) void k_prop(const u32* __restrict__ pin, u32* __restrict__ pout,
                                              float* __restrict__ hout, const float* __restrict__ h0,
                                              const int* __restrict__ off, const int* __restrict__ csr_row,
                                              const float* __restrict__ dinv, int last) {
    __shared__ __align__(16) u32 stage[4][16][64];   // [wave][slot][lane] = 16KB
    int t = threadIdx.x;
    int wv = t >> 6, ln = t & 63;
    int gw = blockIdx.x * 16 + (t >> 4);     // node (grid = N/16 blocks, N%16==0)
    int l = t & 15;
    int lbase = t & 48;
    int s = off[gw], e = off[gw + 1];        // (e-s) % 8 == 0 by construction
    float dv = dinv[gw];
    u32 selfp = pin[(size_t)gw * 16 + l];
    float2 h0v = ((const float2*)h0)[(size_t)gw * 16 + l];

    float acc0 = 0.f, acc1 = 0.f;
    int base = s;
    // main loop: 16 edges per iter, 16 async gathers in flight, no dest VGPRs
    for (; base + 16 <= e; base += 16) {
        int idx = csr_row[base + l];          // 16 distinct indices, 64B coalesced per group
        asm volatile("s_waitcnt lgkmcnt(0)" ::: "memory");   // prior slot reads done before rewrite
        #pragma unroll
        for (int i = 0; i < 16; ++i) {
            int r = __shfl(idx, lbase + i, 64);
            load_lds4(pin + (size_t)r * 16 + l, &stage[wv][i][0]);  // lane ln -> stage[wv][i][ln]
        }
        asm volatile("s_waitcnt vmcnt(0)" ::: "memory");
        #pragma unroll
        for (int i = 0; i < 16; ++i) {
            u32 v = stage[wv][i][ln];
            union { u32 u; float f; } a, b;
            a.u = v << 16; b.u = v & 0xffff0000u;
            acc0 += a.f; acc1 += b.f;
        }
    }
    if (base < e) {   // 8-edge tail (pad8 guarantees exactly one)
        int idx = csr_row[base + (l & 7)];    // lanes 8-15 duplicate 0-7 (broadcast-coalesced)
        asm volatile("s_waitcnt lgkmcnt(0)" ::: "memory");
        #pragma unroll
        for (int i = 0; i < 8; ++i) {
            int r = __shfl(idx, lbase + i, 64);
            load_lds4(pin + (size_t)r * 16 + l, &stage[wv][i][0]);
        }
        asm volatile("s_waitcnt vmcnt(0)" ::: "memory");
        #pragma unroll
        for (int i = 0; i < 8; ++i) {
            u32 v = stage[wv][i][ln];
            union { u32 u; float f; } a, b;
            a.u = v << 16; b.u = v & 0xffff0000u;
            acc0 += a.f; acc1 += b.f;
        }
    }
    acc0 += b2f((u16)selfp);
    acc1 += b2f((u16)(selfp >> 16));
    float hc0 = 0.9f * dv * acc0 + 0.1f * h0v.x;
    float hc1 = 0.9f * dv * acc1 + 0.1f * h0v.y;
    if (last) {
        ((float2*)hout)[(size_t)gw * 16 + l] = make_float2(hc0, hc1);
    } else {
        pout[(size_t)gw * 16 + l] = (u32)f2b(dv * hc0) | ((u32)f2b(dv * hc1) << 16);
    }
}

// ---------------- launch ----------------

extern "C" void kernel_launch(void* const* d_in, const int* in_sizes, int n_in,
                              void* d_out, int out_size, void* d_ws, size_t ws_size,
                              hipStream_t stream) {
    const float* x  = (const float*)d_in[0];
    const int*   ei = (const int*)d_in[1];      // [2][E]
    const float* W1 = (const float*)d_in[2];
    const float* b1 = (const float*)d_in[3];
    const float* Wr = (const float*)d_in[4];
    const float* br = (const float*)d_in[5];
    const float* W2 = (const float*)d_in[6];
    const float* b2 = (const float*)d_in[7];
    float* out = (float*)d_out;

    char* ws = (char*)d_ws;
    size_t off_b = 0;
    auto take = [&](size_t bytes) {
        void* p = ws + off_b;
        off_b += (bytes + 255) & ~(size_t)255;
        return p;
    };

    float* h0      = (float*)take((size_t)N_NODES * OUT_CH * 4);
    u16*   pA      = (u16*)  take((size_t)(N_NODES + 1) * OUT_CH * 2);
    u16*   pB      = (u16*)  take((size_t)(N_NODES + 1) * OUT_CH * 2);
    int*   csr_row = (int*)  take((size_t)EPAD * 4);
    float* dinv    = (float*)take((size_t)N_NODES * 4);
    int*   cnt     = (int*)  take((size_t)N_NODES * 4);
    int*   offs    = (int*)  take((size_t)(N_NODES + 1) * 4);
    int*   bs      = (int*)  take(1024);
    int*   bo      = (int*)  take(1024);
    u16*   W1b     = (u16*)  take((size_t)HID * IN_CH * 2);
    u16*   Wrb     = (u16*)  take((size_t)HID * HID * 2);

    const int* e_row = ei;
    const int* e_col = ei + E_EDGES;

    // 1) merged preprocessing (R17: 6 fewer dispatches; ~3us launch gap each)
    hipMemsetAsync(cnt, 0, (size_t)N_NODES * 4, stream);
    k_cast_all<<<(HID * IN_CH / 4 + HID * HID / 4 + 255) / 256, 256, 0, stream>>>(
        W1, Wr, W1b, Wrb,
        (u32*)(pA + (size_t)N_NODES * OUT_CH), (u32*)(pB + (size_t)N_NODES * OUT_CH));
    k_count_filldummy<<<(EPAD + 255) / 256, 256, 0, stream>>>(e_col, cnt, csr_row);
    const int NB = (N_NODES + 1023) / 1024;  // 98
    k_blocksum<<<NB, 256, 0, stream>>>(cnt, bs, dinv);
    k_scanblocks<<<1, 128, 0, stream>>>(bs, bo, NB);
    k_scanwithin<<<NB, 256, 0, stream>>>(cnt, bo, bs, offs);
    k_fill<<<(E_EDGES + 255) / 256, 256, 0, stream>>>(e_row, e_col, offs, cnt, csr_row);

    // 2) fused MLP: x -> h1 -> xres -> h0, p0 (one pass over x; intermediates in LDS)
    fused_mlp<<<(N_NODES + 63) / 64, 512, 0, stream>>>(x, W1b, b1, Wrb, br, W2, b2,
                                                       dinv, h0, pA, N_NODES);

    // 3) propagation: K steps on packed bf16 p, final step writes fp32 h to out
    const u32* pin = (const u32*)pA;
    for (int s = 0; s < K_STEPS; ++s) {
        int last = (s == K_STEPS - 1);
        u32* pout = (u32*)((s & 1) ? pA : pB);
        k_prop<<<N_NODES / 16, 256, 0, stream>>>(pin, pout, out, h0, offs, csr_row, dinv, last);
        pin = pout;
    }
}